// Round 3
// baseline (393.275 us; speedup 1.0000x reference)
//
#include <hip/hip_runtime.h>
#include <hip/hip_bf16.h>
#include <cstdint>

#define N_NODES 4096
#define F_IN    512
#define F_OUT   64
#define H_HEADS 8
#define JC      4          // j-sweep chunks for k_attn_mfma

constexpr float L2E = 1.44269504088896f;

typedef _Float16 half4_t __attribute__((ext_vector_type(4)));
typedef float    f32x4   __attribute__((ext_vector_type(4)));

__device__ inline float fast_exp2(float a) {
#if __has_builtin(__builtin_amdgcn_exp2f)
    return __builtin_amdgcn_exp2f(a);
#else
    return exp2f(a);
#endif
}

// ---------------- K0: adj int32 -> u64 bitmask per (row, 64-col chunk) ----------------
__global__ __launch_bounds__(256) void k_adj_bitmask(const int* __restrict__ adj,
                                                     unsigned long long* __restrict__ adjw) {
    int lane = threadIdx.x & 63;
    int wid  = (int)((blockIdx.x * blockDim.x + threadIdx.x) >> 6);
    int nwaves = (int)((gridDim.x * blockDim.x) >> 6);
    const int nchunks = N_NODES * (N_NODES / 64);
    for (int c = wid; c < nchunks; c += nwaves) {
        int v = adj[(size_t)c * 64 + lane];
        unsigned long long mask = __ballot(v > 0);
        if (lane == 0) adjw[c] = mask;
    }
}

// ---------------- K1: Wh = x @ W[h] (f32) + fold scores + f16 transposed write ----------------
__global__ __launch_bounds__(256) void k_wh_gemm(const float* __restrict__ x,
                                                 const float* __restrict__ W,
                                                 const float* __restrict__ a_src,
                                                 const float* __restrict__ a_tgt,
                                                 _Float16* __restrict__ WhbT,
                                                 float* __restrict__ s_i,
                                                 float* __restrict__ s_j) {
    __shared__ float xs[64][36];
    __shared__ float wsh[32][64];
    const int h  = blockIdx.y;
    const int rt = blockIdx.x;
    const int t  = threadIdx.x;
    const int o  = t & 63;
    const int g  = t >> 6;

    float acc[16];
    #pragma unroll
    for (int i = 0; i < 16; i++) acc[i] = 0.f;

    const float* Wx = W + (size_t)h * F_IN * F_OUT;

    for (int k0 = 0; k0 < F_IN; k0 += 32) {
        __syncthreads();
        #pragma unroll
        for (int i = 0; i < 8; i++) {
            int idx = t + i * 256;
            int r = idx >> 5, kk = idx & 31;
            xs[r][kk] = x[(size_t)(rt * 64 + r) * F_IN + k0 + kk];
        }
        #pragma unroll
        for (int i = 0; i < 8; i++) {
            int idx = t + i * 256;
            int kk = idx >> 6, oo = idx & 63;
            wsh[kk][oo] = Wx[(size_t)(k0 + kk) * F_OUT + oo];
        }
        __syncthreads();
        #pragma unroll
        for (int k4 = 0; k4 < 8; k4++) {
            float wv0 = wsh[k4 * 4 + 0][o];
            float wv1 = wsh[k4 * 4 + 1][o];
            float wv2 = wsh[k4 * 4 + 2][o];
            float wv3 = wsh[k4 * 4 + 3][o];
            #pragma unroll
            for (int rr = 0; rr < 16; rr++) {
                int r = g * 16 + rr;
                float4 xv = *reinterpret_cast<const float4*>(&xs[r][k4 * 4]);
                acc[rr] = fmaf(xv.x, wv0, acc[rr]);
                acc[rr] = fmaf(xv.y, wv1, acc[rr]);
                acc[rr] = fmaf(xv.z, wv2, acc[rr]);
                acc[rr] = fmaf(xv.w, wv3, acc[rr]);
            }
        }
    }

    const float as = a_src[h * 64 + o];
    const float at = a_tgt[h * 64 + o];
    _Float16 hv[16];
    #pragma unroll
    for (int rr = 0; rr < 16; rr++) {
        float vi = acc[rr] * as;
        float vj = acc[rr] * at;
        #pragma unroll
        for (int mm = 32; mm >= 1; mm >>= 1) {
            vi += __shfl_xor(vi, mm, 64);
            vj += __shfl_xor(vj, mm, 64);
        }
        if (o == 0) {
            int row = rt * 64 + g * 16 + rr;
            s_i[h * N_NODES + row] = vi;
            s_j[h * N_NODES + row] = vj;
        }
        hv[rr] = (_Float16)acc[rr];
    }
    size_t base = ((size_t)(h * 64 + o)) * N_NODES + rt * 64 + g * 16;
    *reinterpret_cast<int4*>(&WhbT[base])     = *reinterpret_cast<const int4*>(&hv[0]);
    *reinterpret_cast<int4*>(&WhbT[base + 8]) = *reinterpret_cast<const int4*>(&hv[8]);
}

// ---------------- K2: per (h,i) rowmax -> negmp = -lrelu(s_i + max_neighbor s_j) * log2(e) ----------------
__global__ __launch_bounds__(256) void k_rowmax(const float* __restrict__ s_i,
                                                const float* __restrict__ s_j,
                                                const unsigned long long* __restrict__ adjw,
                                                float* __restrict__ negmp) {
    const int lane = threadIdx.x & 63;
    const int i    = (int)((blockIdx.x * blockDim.x + threadIdx.x) >> 6);

    float mx[H_HEADS];
    #pragma unroll
    for (int h = 0; h < H_HEADS; h++) mx[h] = -INFINITY;

    for (int c = 0; c < N_NODES / 64; c++) {
        unsigned long long word = adjw[(size_t)i * 64 + c];
        float addm = ((word >> lane) & 1ull) ? 0.0f : -INFINITY;
        #pragma unroll
        for (int h = 0; h < H_HEADS; h++) {
            float sj = s_j[h * N_NODES + c * 64 + lane];
            mx[h] = fmaxf(mx[h], sj + addm);
        }
    }
    #pragma unroll
    for (int h = 0; h < H_HEADS; h++) {
        float v = mx[h];
        #pragma unroll
        for (int mm = 32; mm >= 1; mm >>= 1) v = fmaxf(v, __shfl_xor(v, mm, 64));
        mx[h] = v;
    }
    if (lane == 0) {
        #pragma unroll
        for (int h = 0; h < H_HEADS; h++) {
            float e = s_i[h * N_NODES + i] + mx[h];
            e = fmaxf(e, 0.2f * e);
            negmp[h * N_NODES + i] = -(e * L2E);
        }
    }
}

// ---------------- K3: P in MFMA A-layout + PV via v_mfma_f32_16x16x16f16, j-split + atomics ----------------
// grid (64, 8, JC), block 256 (4 waves). Wave: 16 rows x 64 o, j in [jc*1024, jc*1024+1024).
__global__ __launch_bounds__(256) void k_attn_mfma(const _Float16* __restrict__ WhbT,
                                                   const float* __restrict__ s_i,
                                                   const float* __restrict__ negmp,
                                                   const float* __restrict__ s_j,
                                                   const unsigned long long* __restrict__ adjw,
                                                   float* __restrict__ out,
                                                   float* __restrict__ lsum_glob) {
    const int h    = blockIdx.y;
    const int jc   = blockIdx.z;
    const int t    = threadIdx.x;
    const int lane = t & 63;
    const int w    = t >> 6;
    const int i0   = blockIdx.x * 64 + w * 16;
    const int mrow = lane & 15;
    const int g    = lane >> 4;

    const float si  = s_i[h * N_NODES + i0 + mrow];
    const float nmp = negmp[h * N_NODES + i0 + mrow];
    const float* __restrict__ sjh = s_j + h * N_NODES;
    const unsigned long long* __restrict__ aw = adjw + (size_t)(i0 + mrow) * 64;
    const _Float16* __restrict__ Bh = WhbT + ((size_t)h * 64 + mrow) * N_NODES;

    f32x4 acc0 = {0.f, 0.f, 0.f, 0.f};
    f32x4 acc1 = {0.f, 0.f, 0.f, 0.f};
    f32x4 acc2 = {0.f, 0.f, 0.f, 0.f};
    f32x4 acc3 = {0.f, 0.f, 0.f, 0.f};
    float lsum = 0.f;

    const int NC   = (N_NODES / 64) / JC;   // 16 chunks per block
    const int cbeg = jc * NC;

    for (int c = cbeg; c < cbeg + NC; c++) {
        unsigned long long word = aw[c];
        #pragma unroll
        for (int q = 0; q < 4; q++) {
            const int jb = c * 64 + q * 16;
            float4 sjv = *reinterpret_cast<const float4*>(&sjh[jb + 4 * g]);
            unsigned int nib = (unsigned int)(word >> (q * 16 + 4 * g)) & 0xFu;

            half4_t af;
            #pragma unroll
            for (int tt = 0; tt < 4; tt++) {
                float sjc = (tt == 0) ? sjv.x : (tt == 1) ? sjv.y : (tt == 2) ? sjv.z : sjv.w;
                float e = si + sjc;
                e = fmaxf(e, 0.2f * e);                  // leaky relu
                float p = fast_exp2(fmaf(e, L2E, nmp));  // exp(e - m); m true max => arg <= ~0
                if (!((nib >> tt) & 1u)) p = 0.f;        // adjacency mask
                lsum += p;
                af[tt] = (_Float16)p;
            }

            const size_t bo = (size_t)jb + 4 * g;
            half4_t b0 = *reinterpret_cast<const half4_t*>(&Bh[bo]);
            half4_t b1 = *reinterpret_cast<const half4_t*>(&Bh[bo + 16 * (size_t)N_NODES]);
            half4_t b2 = *reinterpret_cast<const half4_t*>(&Bh[bo + 32 * (size_t)N_NODES]);
            half4_t b3 = *reinterpret_cast<const half4_t*>(&Bh[bo + 48 * (size_t)N_NODES]);

            acc0 = __builtin_amdgcn_mfma_f32_16x16x16f16(af, b0, acc0, 0, 0, 0);
            acc1 = __builtin_amdgcn_mfma_f32_16x16x16f16(af, b1, acc1, 0, 0, 0);
            acc2 = __builtin_amdgcn_mfma_f32_16x16x16f16(af, b2, acc2, 0, 0, 0);
            acc3 = __builtin_amdgcn_mfma_f32_16x16x16f16(af, b3, acc3, 0, 0, 0);
        }
    }

    // denominator partial: after xors every lane holds full chunk-sum for row mrow
    lsum += __shfl_xor(lsum, 16, 64);
    lsum += __shfl_xor(lsum, 32, 64);
    if (lane < 16) atomicAdd(&lsum_glob[h * N_NODES + i0 + mrow], lsum);

    #pragma unroll
    for (int r = 0; r < 4; r++) {
        int row   = i0 + 4 * g + r;
        size_t ob = ((size_t)h * N_NODES + row) * 64 + mrow;
        atomicAdd(&out[ob + 0],  acc0[r]);
        atomicAdd(&out[ob + 16], acc1[r]);
        atomicAdd(&out[ob + 32], acc2[r]);
        atomicAdd(&out[ob + 48], acc3[r]);
    }
}

// ---------------- K4: normalize out by lsum ----------------
__global__ __launch_bounds__(256) void k_norm(float* __restrict__ out,
                                              const float* __restrict__ lsum) {
    int idx = blockIdx.x * 256 + threadIdx.x;        // one float4 per thread
    int row = idx >> 4;                              // 16 float4 per row; row = h*4096+i
    float inv = 1.0f / lsum[row];
    float4* ov = reinterpret_cast<float4*>(out);
    float4 v = ov[idx];
    v.x *= inv; v.y *= inv; v.z *= inv; v.w *= inv;
    ov[idx] = v;
}

// ---------------- launch ----------------
extern "C" void kernel_launch(void* const* d_in, const int* in_sizes, int n_in,
                              void* d_out, int out_size, void* d_ws, size_t ws_size,
                              hipStream_t stream) {
    const float* x     = (const float*)d_in[0];
    const int*   adj   = (const int*)d_in[1];
    const float* W     = (const float*)d_in[2];
    const float* a_src = (const float*)d_in[3];
    const float* a_tgt = (const float*)d_in[4];
    float* out = (float*)d_out;

    char* ws = (char*)d_ws;
    _Float16* WhbT = (_Float16*)(ws);                               // 4 MB: [h][o][j] f16
    float* s_i     = (float*)(ws + 4194304);                        // 128 KB
    float* s_j     = (float*)(ws + 4325376);                        // 128 KB
    float* negmp   = (float*)(ws + 4456448);                        // 128 KB
    float* lsum    = (float*)(ws + 4587520);                        // 128 KB
    unsigned long long* adjw = (unsigned long long*)(ws + 4718592); // 2 MB

    hipMemsetAsync(out, 0, (size_t)H_HEADS * N_NODES * F_OUT * 4, stream);
    hipMemsetAsync(lsum, 0, (size_t)H_HEADS * N_NODES * 4, stream);

    k_adj_bitmask<<<2048, 256, 0, stream>>>(adj, adjw);
    k_wh_gemm<<<dim3(N_NODES / 64, H_HEADS), 256, 0, stream>>>(x, W, a_src, a_tgt, WhbT, s_i, s_j);
    k_rowmax<<<1024, 256, 0, stream>>>(s_i, s_j, adjw, negmp);
    k_attn_mfma<<<dim3(N_NODES / 64, H_HEADS, JC), 256, 0, stream>>>(WhbT, s_i, negmp, s_j, adjw, out, lsum);
    k_norm<<<(H_HEADS * N_NODES * F_OUT / 4) / 256, 256, 0, stream>>>(out, lsum);
}

// Round 4
// 261.628 us; speedup vs baseline: 1.5032x; 1.5032x over previous
//
#include <hip/hip_runtime.h>
#include <hip/hip_bf16.h>
#include <cstdint>

#define N_NODES 4096
#define F_IN    512
#define F_OUT   64
#define H_HEADS 8
#define JC      2          // j-sweep chunks for k_attn_mfma

constexpr float L2E = 1.44269504088896f;

typedef _Float16 half4_t __attribute__((ext_vector_type(4)));
typedef _Float16 half8_t __attribute__((ext_vector_type(8)));
typedef float    f32x4   __attribute__((ext_vector_type(4)));

__device__ inline float fast_exp2(float a) {
#if __has_builtin(__builtin_amdgcn_exp2f)
    return __builtin_amdgcn_exp2f(a);
#else
    return exp2f(a);
#endif
}

// ---------------- K0: adj int32 -> u64 bitmask, row-major + transposed ----------------
__global__ __launch_bounds__(256) void k_adj_bitmask(const int* __restrict__ adj,
                                                     unsigned long long* __restrict__ adjw,
                                                     unsigned long long* __restrict__ adjwT) {
    int lane = threadIdx.x & 63;
    int wid  = (int)((blockIdx.x * blockDim.x + threadIdx.x) >> 6);
    int nwaves = (int)((gridDim.x * blockDim.x) >> 6);
    const int nchunks = N_NODES * (N_NODES / 64);
    for (int cf = wid; cf < nchunks; cf += nwaves) {
        int v = adj[(size_t)cf * 64 + lane];
        unsigned long long mask = __ballot(v > 0);
        if (lane == 0) {
            int i = cf >> 6, c = cf & 63;
            adjw[cf] = mask;                              // [i][c] for k_rowmax
            adjwT[(size_t)c * N_NODES + i] = mask;        // [c][i] for k_attn
        }
    }
}

// ---------------- K1: Wh = x @ W[h] (f32) + scores + FRAGMENT-LINEAR f16 write ----------------
// Fragment layout per head (262144 f16): [c(64)][q(4)][l(64)][otile(4)][t(4)]
// element (j, o): c=j>>6, q=(j>>4)&3, l=((j>>2)&3)*16 + (o&15), otile=o>>4, t=j&3
__global__ __launch_bounds__(256) void k_wh_gemm(const float* __restrict__ x,
                                                 const float* __restrict__ W,
                                                 const float* __restrict__ a_src,
                                                 const float* __restrict__ a_tgt,
                                                 _Float16* __restrict__ WhFrag,
                                                 float* __restrict__ s_i,
                                                 float* __restrict__ s_j) {
    __shared__ float xs[64][36];
    __shared__ float wsh[32][64];
    const int h  = blockIdx.y;
    const int rt = blockIdx.x;          // this block's rows ARE j-nodes rt*64..+63  (c = rt)
    const int t  = threadIdx.x;
    const int o  = t & 63;
    const int g  = t >> 6;              // wave id == q

    float acc[16];
    #pragma unroll
    for (int i = 0; i < 16; i++) acc[i] = 0.f;

    const float* Wx = W + (size_t)h * F_IN * F_OUT;

    for (int k0 = 0; k0 < F_IN; k0 += 32) {
        __syncthreads();
        #pragma unroll
        for (int i = 0; i < 8; i++) {
            int idx = t + i * 256;
            int r = idx >> 5, kk = idx & 31;
            xs[r][kk] = x[(size_t)(rt * 64 + r) * F_IN + k0 + kk];
        }
        #pragma unroll
        for (int i = 0; i < 8; i++) {
            int idx = t + i * 256;
            int kk = idx >> 6, oo = idx & 63;
            wsh[kk][oo] = Wx[(size_t)(k0 + kk) * F_OUT + oo];
        }
        __syncthreads();
        #pragma unroll
        for (int k4 = 0; k4 < 8; k4++) {
            float wv0 = wsh[k4 * 4 + 0][o];
            float wv1 = wsh[k4 * 4 + 1][o];
            float wv2 = wsh[k4 * 4 + 2][o];
            float wv3 = wsh[k4 * 4 + 3][o];
            #pragma unroll
            for (int rr = 0; rr < 16; rr++) {
                int r = g * 16 + rr;
                float4 xv = *reinterpret_cast<const float4*>(&xs[r][k4 * 4]);
                acc[rr] = fmaf(xv.x, wv0, acc[rr]);
                acc[rr] = fmaf(xv.y, wv1, acc[rr]);
                acc[rr] = fmaf(xv.z, wv2, acc[rr]);
                acc[rr] = fmaf(xv.w, wv3, acc[rr]);
            }
        }
    }

    // scores (f32, full precision)
    const float as = a_src[h * 64 + o];
    const float at = a_tgt[h * 64 + o];
    half4_t hv4[4];
    #pragma unroll
    for (int rr = 0; rr < 16; rr++) {
        float vi = acc[rr] * as;
        float vj = acc[rr] * at;
        #pragma unroll
        for (int mm = 32; mm >= 1; mm >>= 1) {
            vi += __shfl_xor(vi, mm, 64);
            vj += __shfl_xor(vj, mm, 64);
        }
        if (o == 0) {
            int row = rt * 64 + g * 16 + rr;
            s_i[h * N_NODES + row] = vi;
            s_j[h * N_NODES + row] = vj;
        }
        hv4[rr >> 2][rr & 3] = (_Float16)acc[rr];
    }
    // fragment-linear write: thread holds j = rt*64 + g*16 + rr, o = lane.
    // rr = 4a+b -> l = a*16 + (o&15), t = b (4 contiguous f16 per a)
    size_t qbase = (size_t)h * (N_NODES * 64) + ((size_t)rt * 4 + g) * 1024;
    #pragma unroll
    for (int a = 0; a < 4; a++) {
        size_t off = qbase + (size_t)(a * 16 + (o & 15)) * 16 + (o >> 4) * 4;
        *reinterpret_cast<int2*>(&WhFrag[off]) = *reinterpret_cast<const int2*>(&hv4[a]);
    }
}

// ---------------- K2: per (h,i) rowmax -> negmp = -lrelu(s_i + max_neighbor s_j) * log2(e) ----------------
__global__ __launch_bounds__(256) void k_rowmax(const float* __restrict__ s_i,
                                                const float* __restrict__ s_j,
                                                const unsigned long long* __restrict__ adjw,
                                                float* __restrict__ negmp) {
    const int lane = threadIdx.x & 63;
    const int i    = (int)((blockIdx.x * blockDim.x + threadIdx.x) >> 6);

    float mx[H_HEADS];
    #pragma unroll
    for (int h = 0; h < H_HEADS; h++) mx[h] = -INFINITY;

    for (int c = 0; c < N_NODES / 64; c++) {
        unsigned long long word = adjw[(size_t)i * 64 + c];
        float addm = ((word >> lane) & 1ull) ? 0.0f : -INFINITY;
        #pragma unroll
        for (int h = 0; h < H_HEADS; h++) {
            float sj = s_j[h * N_NODES + c * 64 + lane];
            mx[h] = fmaxf(mx[h], sj + addm);
        }
    }
    #pragma unroll
    for (int h = 0; h < H_HEADS; h++) {
        float v = mx[h];
        #pragma unroll
        for (int mm = 32; mm >= 1; mm >>= 1) v = fmaxf(v, __shfl_xor(v, mm, 64));
        mx[h] = v;
    }
    if (lane == 0) {
        #pragma unroll
        for (int h = 0; h < H_HEADS; h++) {
            float e = s_i[h * N_NODES + i] + mx[h];
            e = fmaxf(e, 0.2f * e);
            negmp[h * N_NODES + i] = -(e * L2E);
        }
    }
}

// ---------------- K3: P in MFMA A-layout + PV, fully coalesced B loads ----------------
// grid (64, 8, JC), block 256 (4 waves). Wave: 16 rows x 64 o, j-chunk sweep.
__global__ __launch_bounds__(256, 4) void k_attn_mfma(const _Float16* __restrict__ WhFrag,
                                                      const float* __restrict__ s_i,
                                                      const float* __restrict__ negmp,
                                                      const float* __restrict__ s_j,
                                                      const unsigned long long* __restrict__ adjwT,
                                                      float* __restrict__ out,
                                                      float* __restrict__ lsum_glob) {
    const int h    = blockIdx.y;
    const int jc   = blockIdx.z;
    const int t    = threadIdx.x;
    const int lane = t & 63;
    const int w    = t >> 6;
    const int i0   = blockIdx.x * 64 + w * 16;
    const int mrow = lane & 15;
    const int g    = lane >> 4;

    const float si  = s_i[h * N_NODES + i0 + mrow];
    const float nmp = negmp[h * N_NODES + i0 + mrow];
    const float* __restrict__ sjh = s_j + h * N_NODES;
    const _Float16* __restrict__ Bh = WhFrag + (size_t)h * (N_NODES * 64);

    f32x4 acc0 = {0.f, 0.f, 0.f, 0.f};
    f32x4 acc1 = {0.f, 0.f, 0.f, 0.f};
    f32x4 acc2 = {0.f, 0.f, 0.f, 0.f};
    f32x4 acc3 = {0.f, 0.f, 0.f, 0.f};
    float lsum = 0.f;

    const int NC   = (N_NODES / 64) / JC;   // 32 chunks per block
    const int cbeg = jc * NC;

    for (int c = cbeg; c < cbeg + NC; c++) {
        unsigned long long word = adjwT[(size_t)c * N_NODES + i0 + mrow];  // coalesced
        const _Float16* __restrict__ Bc = Bh + (size_t)c * 4096;
        #pragma unroll
        for (int q = 0; q < 4; q++) {
            const int jb = c * 64 + q * 16;
            float4 sjv = *reinterpret_cast<const float4*>(&sjh[jb + 4 * g]);
            unsigned int nib = (unsigned int)(word >> (q * 16 + 4 * g)) & 0xFu;

            // lane's 32 contiguous bytes: [otile(4)][t(4)] f16
            const _Float16* __restrict__ Bq = Bc + q * 1024 + lane * 16;
            half8_t B01 = *reinterpret_cast<const half8_t*>(Bq);
            half8_t B23 = *reinterpret_cast<const half8_t*>(Bq + 8);
            half4_t b0 = __builtin_shufflevector(B01, B01, 0, 1, 2, 3);
            half4_t b1 = __builtin_shufflevector(B01, B01, 4, 5, 6, 7);
            half4_t b2 = __builtin_shufflevector(B23, B23, 0, 1, 2, 3);
            half4_t b3 = __builtin_shufflevector(B23, B23, 4, 5, 6, 7);

            half4_t af;
            #pragma unroll
            for (int tt = 0; tt < 4; tt++) {
                float sjc = (tt == 0) ? sjv.x : (tt == 1) ? sjv.y : (tt == 2) ? sjv.z : sjv.w;
                float e = si + sjc;
                e = fmaxf(e, 0.2f * e);                  // leaky relu
                float p = fast_exp2(fmaf(e, L2E, nmp));  // exp(e - m), m = true row max
                if (!((nib >> tt) & 1u)) p = 0.f;        // adjacency mask
                lsum += p;
                af[tt] = (_Float16)p;
            }

            acc0 = __builtin_amdgcn_mfma_f32_16x16x16f16(af, b0, acc0, 0, 0, 0);
            acc1 = __builtin_amdgcn_mfma_f32_16x16x16f16(af, b1, acc1, 0, 0, 0);
            acc2 = __builtin_amdgcn_mfma_f32_16x16x16f16(af, b2, acc2, 0, 0, 0);
            acc3 = __builtin_amdgcn_mfma_f32_16x16x16f16(af, b3, acc3, 0, 0, 0);
        }
    }

    lsum += __shfl_xor(lsum, 16, 64);
    lsum += __shfl_xor(lsum, 32, 64);
    if (lane < 16) atomicAdd(&lsum_glob[h * N_NODES + i0 + mrow], lsum);

    #pragma unroll
    for (int r = 0; r < 4; r++) {
        int row   = i0 + 4 * g + r;
        size_t ob = ((size_t)h * N_NODES + row) * 64 + mrow;
        atomicAdd(&out[ob + 0],  acc0[r]);
        atomicAdd(&out[ob + 16], acc1[r]);
        atomicAdd(&out[ob + 32], acc2[r]);
        atomicAdd(&out[ob + 48], acc3[r]);
    }
}

// ---------------- K4: normalize out by lsum ----------------
__global__ __launch_bounds__(256) void k_norm(float* __restrict__ out,
                                              const float* __restrict__ lsum) {
    int idx = blockIdx.x * 256 + threadIdx.x;
    int row = idx >> 4;
    float inv = 1.0f / lsum[row];
    float4* ov = reinterpret_cast<float4*>(out);
    float4 v = ov[idx];
    v.x *= inv; v.y *= inv; v.z *= inv; v.w *= inv;
    ov[idx] = v;
}

// ---------------- launch ----------------
extern "C" void kernel_launch(void* const* d_in, const int* in_sizes, int n_in,
                              void* d_out, int out_size, void* d_ws, size_t ws_size,
                              hipStream_t stream) {
    const float* x     = (const float*)d_in[0];
    const int*   adj   = (const int*)d_in[1];
    const float* W     = (const float*)d_in[2];
    const float* a_src = (const float*)d_in[3];
    const float* a_tgt = (const float*)d_in[4];
    float* out = (float*)d_out;

    char* ws = (char*)d_ws;
    _Float16* WhFrag = (_Float16*)(ws);                              // 4 MB fragment-linear
    float* s_i       = (float*)(ws + 4194304);                       // 128 KB
    float* s_j       = (float*)(ws + 4325376);                       // 128 KB
    float* negmp     = (float*)(ws + 4456448);                       // 128 KB
    float* lsum      = (float*)(ws + 4587520);                       // 128 KB
    unsigned long long* adjw  = (unsigned long long*)(ws + 4718592); // 2 MB [i][c]
    unsigned long long* adjwT = (unsigned long long*)(ws + 6815744); // 2 MB [c][i]

    hipMemsetAsync(out, 0, (size_t)H_HEADS * N_NODES * F_OUT * 4, stream);
    hipMemsetAsync(lsum, 0, (size_t)H_HEADS * N_NODES * 4, stream);

    k_adj_bitmask<<<2048, 256, 0, stream>>>(adj, adjw, adjwT);
    k_wh_gemm<<<dim3(N_NODES / 64, H_HEADS), 256, 0, stream>>>(x, W, a_src, a_tgt, WhFrag, s_i, s_j);
    k_rowmax<<<1024, 256, 0, stream>>>(s_i, s_j, adjw, negmp);
    k_attn_mfma<<<dim3(N_NODES / 64, H_HEADS, JC), 256, 0, stream>>>(WhFrag, s_i, negmp, s_j, adjwT, out, lsum);
    k_norm<<<(H_HEADS * N_NODES * F_OUT / 4) / 256, 256, 0, stream>>>(out, lsum);
}

// Round 5
// 151.521 us; speedup vs baseline: 2.5955x; 1.7267x over previous
//
#include <hip/hip_runtime.h>
#include <hip/hip_bf16.h>
#include <cstdint>

#define N_NODES 4096
#define F_IN    512
#define F_OUT   64
#define H_HEADS 8
#define JC      2          // j-sweep chunks for k_attn_mfma

constexpr float L2E = 1.44269504088896f;

typedef _Float16 half4_t __attribute__((ext_vector_type(4)));
typedef _Float16 half8_t __attribute__((ext_vector_type(8)));
typedef float    f32x4   __attribute__((ext_vector_type(4)));

__device__ inline float fast_exp2(float a) {
#if __has_builtin(__builtin_amdgcn_exp2f)
    return __builtin_amdgcn_exp2f(a);
#else
    return exp2f(a);
#endif
}

// ---------------- K0: adj int32 -> u64 bitmask, row-major + transposed ----------------
__global__ __launch_bounds__(256) void k_adj_bitmask(const int* __restrict__ adj,
                                                     unsigned long long* __restrict__ adjw,
                                                     unsigned long long* __restrict__ adjwT) {
    int lane = threadIdx.x & 63;
    int wid  = (int)((blockIdx.x * blockDim.x + threadIdx.x) >> 6);
    int nwaves = (int)((gridDim.x * blockDim.x) >> 6);
    const int nchunks = N_NODES * (N_NODES / 64);
    for (int cf = wid; cf < nchunks; cf += nwaves) {
        int v = adj[(size_t)cf * 64 + lane];
        unsigned long long mask = __ballot(v > 0);
        if (lane == 0) {
            int i = cf >> 6, c = cf & 63;
            adjw[cf] = mask;                              // [i][c] for k_rowmax
            adjwT[(size_t)c * N_NODES + i] = mask;        // [c][i] for k_attn
        }
    }
}

// ---------------- K0b: pack x -> f16 A-fragments [kt(16)][mt(256)][lane(64)][t(8)] ----------------
// value = x[mt*16 + (lane&15)][kt*32 + 8*(lane>>4) + t]  (custom k-map psi(g,t)=8g+t)
__global__ __launch_bounds__(256) void k_xpack(const float* __restrict__ x,
                                               _Float16* __restrict__ xfrag) {
    int gid = blockIdx.x * 256 + threadIdx.x;            // 0 .. 16*256*64-1
    int kt   = gid >> 14;
    int mt   = (gid >> 6) & 255;
    int lane = gid & 63;
    int r = lane & 15, g = lane >> 4;
    const float* src = x + (size_t)(mt * 16 + r) * F_IN + kt * 32 + 8 * g;
    float4 v0 = *reinterpret_cast<const float4*>(src);
    float4 v1 = *reinterpret_cast<const float4*>(src + 4);
    half8_t hv;
    hv[0] = (_Float16)v0.x; hv[1] = (_Float16)v0.y; hv[2] = (_Float16)v0.z; hv[3] = (_Float16)v0.w;
    hv[4] = (_Float16)v1.x; hv[5] = (_Float16)v1.y; hv[6] = (_Float16)v1.z; hv[7] = (_Float16)v1.w;
    *reinterpret_cast<half8_t*>(&xfrag[(size_t)gid * 8]) = hv;
}

// ---------------- K0c: pack W -> f16 B-fragments [h][kt(16)][ntile(4)][lane(64)][t(8)] ----------------
// value = W[h][kt*32 + 8*(lane>>4) + t][ntile*16 + (lane&15)]
__global__ __launch_bounds__(256) void k_wpack(const float* __restrict__ W,
                                               _Float16* __restrict__ wfrag) {
    int gid = blockIdx.x * 256 + threadIdx.x;            // 0 .. 8*16*4*64-1
    int h     = gid >> 12;
    int kt    = (gid >> 8) & 15;
    int ntile = (gid >> 6) & 3;
    int lane  = gid & 63;
    int c0 = lane & 15, g = lane >> 4;
    const float* src = W + ((size_t)h * F_IN + kt * 32 + 8 * g) * F_OUT + ntile * 16 + c0;
    half8_t hv;
    #pragma unroll
    for (int t = 0; t < 8; t++) hv[t] = (_Float16)src[(size_t)t * F_OUT];
    *reinterpret_cast<half8_t*>(&wfrag[(size_t)gid * 8]) = hv;
}

// ---------------- K1: Wh = x @ W[h] via MFMA 16x16x32, pure-register ----------------
// grid (64, 8), block 256 (4 waves). Wave: rows j0 = rt*64 + w*16 .. +15, all 64 o, one head.
// Epilogue: WhFrag [h][c(64)][q(4)][l(64)][otile(4)][t(4)]  (same layout k_attn consumes)
__global__ __launch_bounds__(256) void k_wh_mfma(const _Float16* __restrict__ xfrag,
                                                 const _Float16* __restrict__ wfrag,
                                                 const float* __restrict__ a_src,
                                                 const float* __restrict__ a_tgt,
                                                 _Float16* __restrict__ WhFrag,
                                                 float* __restrict__ s_i,
                                                 float* __restrict__ s_j) {
    const int h    = blockIdx.y;
    const int rt   = blockIdx.x;
    const int t    = threadIdx.x;
    const int lane = t & 63;
    const int w    = t >> 6;
    const int mt   = rt * 4 + w;            // 16-row m-tile index (0..255)
    const int c0   = lane & 15;
    const int gl   = lane >> 4;

    f32x4 acc0 = {0.f, 0.f, 0.f, 0.f};
    f32x4 acc1 = {0.f, 0.f, 0.f, 0.f};
    f32x4 acc2 = {0.f, 0.f, 0.f, 0.f};
    f32x4 acc3 = {0.f, 0.f, 0.f, 0.f};

    const _Float16* __restrict__ Af = xfrag + (size_t)mt * 512 + (size_t)lane * 8;
    const _Float16* __restrict__ Bf = wfrag + (size_t)h * (16 * 4 * 512) + (size_t)lane * 8;

    #pragma unroll
    for (int kt = 0; kt < 16; kt++) {
        half8_t a  = *reinterpret_cast<const half8_t*>(Af + (size_t)kt * (256 * 512));
        const _Float16* Bk = Bf + (size_t)kt * 2048;
        half8_t b0 = *reinterpret_cast<const half8_t*>(Bk);
        half8_t b1 = *reinterpret_cast<const half8_t*>(Bk + 512);
        half8_t b2 = *reinterpret_cast<const half8_t*>(Bk + 1024);
        half8_t b3 = *reinterpret_cast<const half8_t*>(Bk + 1536);
        acc0 = __builtin_amdgcn_mfma_f32_16x16x32_f16(a, b0, acc0, 0, 0, 0);
        acc1 = __builtin_amdgcn_mfma_f32_16x16x32_f16(a, b1, acc1, 0, 0, 0);
        acc2 = __builtin_amdgcn_mfma_f32_16x16x32_f16(a, b2, acc2, 0, 0, 0);
        acc3 = __builtin_amdgcn_mfma_f32_16x16x32_f16(a, b3, acc3, 0, 0, 0);
    }

    // D layout: col = c0, rows = 4*gl + reg  ->  Wh[j0 + 4*gl + reg][ntile*16 + c0]
    // scores: vi[reg] = sum_ntile acc[ntile][reg] * a_src[.. ntile*16 + c0], reduce over c0
    const float as0 = a_src[h * 64 + c0],      at0 = a_tgt[h * 64 + c0];
    const float as1 = a_src[h * 64 + 16 + c0], at1 = a_tgt[h * 64 + 16 + c0];
    const float as2 = a_src[h * 64 + 32 + c0], at2 = a_tgt[h * 64 + 32 + c0];
    const float as3 = a_src[h * 64 + 48 + c0], at3 = a_tgt[h * 64 + 48 + c0];

    #pragma unroll
    for (int reg = 0; reg < 4; reg++) {
        float vi = acc0[reg] * as0 + acc1[reg] * as1 + acc2[reg] * as2 + acc3[reg] * as3;
        float vj = acc0[reg] * at0 + acc1[reg] * at1 + acc2[reg] * at2 + acc3[reg] * at3;
        #pragma unroll
        for (int mm = 8; mm >= 1; mm >>= 1) {
            vi += __shfl_xor(vi, mm, 64);
            vj += __shfl_xor(vj, mm, 64);
        }
        if (c0 == 0) {
            int row = mt * 16 + 4 * gl + reg;
            s_i[h * N_NODES + row] = vi;
            s_j[h * N_NODES + row] = vj;
        }
    }

    // WhFrag write: qbase = h*262144 + mt*1024; lane's 32 B at elem qbase + lane*16
    half8_t h01, h23;
    #pragma unroll
    for (int reg = 0; reg < 4; reg++) {
        h01[reg]     = (_Float16)acc0[reg];
        h01[4 + reg] = (_Float16)acc1[reg];
        h23[reg]     = (_Float16)acc2[reg];
        h23[4 + reg] = (_Float16)acc3[reg];
    }
    _Float16* dst = WhFrag + (size_t)h * (N_NODES * 64) + (size_t)mt * 1024 + (size_t)lane * 16;
    *reinterpret_cast<half8_t*>(dst)     = h01;
    *reinterpret_cast<half8_t*>(dst + 8) = h23;
}

// ---------------- K2: per (h,i) rowmax -> negmp, 4 rows per wave (s_j reuse) ----------------
__global__ __launch_bounds__(256) void k_rowmax(const float* __restrict__ s_i,
                                                const float* __restrict__ s_j,
                                                const unsigned long long* __restrict__ adjw,
                                                float* __restrict__ negmp) {
    const int lane = threadIdx.x & 63;
    const int wv   = (int)((blockIdx.x * blockDim.x + threadIdx.x) >> 6);
    const int i0   = wv * 4;

    float mx[4][H_HEADS];
    #pragma unroll
    for (int ii = 0; ii < 4; ii++)
        #pragma unroll
        for (int h = 0; h < H_HEADS; h++) mx[ii][h] = -INFINITY;

    for (int c = 0; c < N_NODES / 64; c++) {
        unsigned long long wd[4];
        #pragma unroll
        for (int ii = 0; ii < 4; ii++) wd[ii] = adjw[(size_t)(i0 + ii) * 64 + c];
        float pen[4];
        #pragma unroll
        for (int ii = 0; ii < 4; ii++) pen[ii] = ((wd[ii] >> lane) & 1ull) ? 0.0f : -INFINITY;
        #pragma unroll
        for (int h = 0; h < H_HEADS; h++) {
            float sj = s_j[h * N_NODES + c * 64 + lane];
            #pragma unroll
            for (int ii = 0; ii < 4; ii++)
                mx[ii][h] = fmaxf(mx[ii][h], sj + pen[ii]);
        }
    }
    #pragma unroll
    for (int ii = 0; ii < 4; ii++)
        #pragma unroll
        for (int h = 0; h < H_HEADS; h++) {
            float v = mx[ii][h];
            #pragma unroll
            for (int mm = 32; mm >= 1; mm >>= 1) v = fmaxf(v, __shfl_xor(v, mm, 64));
            mx[ii][h] = v;
        }
    if (lane == 0) {
        #pragma unroll
        for (int ii = 0; ii < 4; ii++)
            #pragma unroll
            for (int h = 0; h < H_HEADS; h++) {
                float e = s_i[h * N_NODES + i0 + ii] + mx[ii][h];
                e = fmaxf(e, 0.2f * e);
                negmp[h * N_NODES + i0 + ii] = -(e * L2E);
            }
    }
}

// ---------------- K3: P in MFMA A-layout + PV, fully coalesced B loads ----------------
__global__ __launch_bounds__(256, 4) void k_attn_mfma(const _Float16* __restrict__ WhFrag,
                                                      const float* __restrict__ s_i,
                                                      const float* __restrict__ negmp,
                                                      const float* __restrict__ s_j,
                                                      const unsigned long long* __restrict__ adjwT,
                                                      float* __restrict__ out,
                                                      float* __restrict__ lsum_glob) {
    const int h    = blockIdx.y;
    const int jc   = blockIdx.z;
    const int t    = threadIdx.x;
    const int lane = t & 63;
    const int w    = t >> 6;
    const int i0   = blockIdx.x * 64 + w * 16;
    const int mrow = lane & 15;
    const int g    = lane >> 4;

    const float si  = s_i[h * N_NODES + i0 + mrow];
    const float nmp = negmp[h * N_NODES + i0 + mrow];
    const float* __restrict__ sjh = s_j + h * N_NODES;
    const _Float16* __restrict__ Bh = WhFrag + (size_t)h * (N_NODES * 64);

    f32x4 acc0 = {0.f, 0.f, 0.f, 0.f};
    f32x4 acc1 = {0.f, 0.f, 0.f, 0.f};
    f32x4 acc2 = {0.f, 0.f, 0.f, 0.f};
    f32x4 acc3 = {0.f, 0.f, 0.f, 0.f};
    float lsum = 0.f;

    const int NC   = (N_NODES / 64) / JC;
    const int cbeg = jc * NC;

    for (int c = cbeg; c < cbeg + NC; c++) {
        unsigned long long word = adjwT[(size_t)c * N_NODES + i0 + mrow];
        const _Float16* __restrict__ Bc = Bh + (size_t)c * 4096;
        #pragma unroll
        for (int q = 0; q < 4; q++) {
            const int jb = c * 64 + q * 16;
            float4 sjv = *reinterpret_cast<const float4*>(&sjh[jb + 4 * g]);
            unsigned int nib = (unsigned int)(word >> (q * 16 + 4 * g)) & 0xFu;

            const _Float16* __restrict__ Bq = Bc + q * 1024 + lane * 16;
            half8_t B01 = *reinterpret_cast<const half8_t*>(Bq);
            half8_t B23 = *reinterpret_cast<const half8_t*>(Bq + 8);
            half4_t b0 = __builtin_shufflevector(B01, B01, 0, 1, 2, 3);
            half4_t b1 = __builtin_shufflevector(B01, B01, 4, 5, 6, 7);
            half4_t b2 = __builtin_shufflevector(B23, B23, 0, 1, 2, 3);
            half4_t b3 = __builtin_shufflevector(B23, B23, 4, 5, 6, 7);

            half4_t af;
            #pragma unroll
            for (int tt = 0; tt < 4; tt++) {
                float sjc = (tt == 0) ? sjv.x : (tt == 1) ? sjv.y : (tt == 2) ? sjv.z : sjv.w;
                float e = si + sjc;
                e = fmaxf(e, 0.2f * e);
                float p = fast_exp2(fmaf(e, L2E, nmp));
                if (!((nib >> tt) & 1u)) p = 0.f;
                lsum += p;
                af[tt] = (_Float16)p;
            }

            acc0 = __builtin_amdgcn_mfma_f32_16x16x16f16(af, b0, acc0, 0, 0, 0);
            acc1 = __builtin_amdgcn_mfma_f32_16x16x16f16(af, b1, acc1, 0, 0, 0);
            acc2 = __builtin_amdgcn_mfma_f32_16x16x16f16(af, b2, acc2, 0, 0, 0);
            acc3 = __builtin_amdgcn_mfma_f32_16x16x16f16(af, b3, acc3, 0, 0, 0);
        }
    }

    lsum += __shfl_xor(lsum, 16, 64);
    lsum += __shfl_xor(lsum, 32, 64);
    if (lane < 16) atomicAdd(&lsum_glob[h * N_NODES + i0 + mrow], lsum);

    #pragma unroll
    for (int r = 0; r < 4; r++) {
        int row   = i0 + 4 * g + r;
        size_t ob = ((size_t)h * N_NODES + row) * 64 + mrow;
        atomicAdd(&out[ob + 0],  acc0[r]);
        atomicAdd(&out[ob + 16], acc1[r]);
        atomicAdd(&out[ob + 32], acc2[r]);
        atomicAdd(&out[ob + 48], acc3[r]);
    }
}

// ---------------- K4: normalize out by lsum ----------------
__global__ __launch_bounds__(256) void k_norm(float* __restrict__ out,
                                              const float* __restrict__ lsum) {
    int idx = blockIdx.x * 256 + threadIdx.x;
    int row = idx >> 4;
    float inv = 1.0f / lsum[row];
    float4* ov = reinterpret_cast<float4*>(out);
    float4 v = ov[idx];
    v.x *= inv; v.y *= inv; v.z *= inv; v.w *= inv;
    ov[idx] = v;
}

// ---------------- launch ----------------
extern "C" void kernel_launch(void* const* d_in, const int* in_sizes, int n_in,
                              void* d_out, int out_size, void* d_ws, size_t ws_size,
                              hipStream_t stream) {
    const float* x     = (const float*)d_in[0];
    const int*   adj   = (const int*)d_in[1];
    const float* W     = (const float*)d_in[2];
    const float* a_src = (const float*)d_in[3];
    const float* a_tgt = (const float*)d_in[4];
    float* out = (float*)d_out;

    char* ws = (char*)d_ws;
    _Float16* WhFrag = (_Float16*)(ws);                               // 4 MB
    _Float16* xfrag  = (_Float16*)(ws + 4194304);                     // 4 MB
    _Float16* wfrag  = (_Float16*)(ws + 8388608);                     // 512 KB
    float* s_i       = (float*)(ws + 8912896);                        // 128 KB
    float* s_j       = (float*)(ws + 9043968);                        // 128 KB
    float* negmp     = (float*)(ws + 9175040);                        // 128 KB
    float* lsum      = (float*)(ws + 9306112);                        // 128 KB
    unsigned long long* adjw  = (unsigned long long*)(ws + 9437184);  // 2 MB [i][c]
    unsigned long long* adjwT = (unsigned long long*)(ws + 11534336); // 2 MB [c][i]

    hipMemsetAsync(out, 0, (size_t)H_HEADS * N_NODES * F_OUT * 4, stream);
    hipMemsetAsync(lsum, 0, (size_t)H_HEADS * N_NODES * 4, stream);

    k_adj_bitmask<<<2048, 256, 0, stream>>>(adj, adjw, adjwT);
    k_xpack<<<1024, 256, 0, stream>>>(x, xfrag);
    k_wpack<<<128, 256, 0, stream>>>(W, wfrag);
    k_wh_mfma<<<dim3(N_NODES / 64, H_HEADS), 256, 0, stream>>>(xfrag, wfrag, a_src, a_tgt, WhFrag, s_i, s_j);
    k_rowmax<<<256, 256, 0, stream>>>(s_i, s_j, adjw, negmp);
    k_attn_mfma<<<dim3(N_NODES / 64, H_HEADS, JC), 256, 0, stream>>>(WhFrag, s_i, negmp, s_j, adjwT, out, lsum);
    k_norm<<<(H_HEADS * N_NODES * F_OUT / 4) / 256, 256, 0, stream>>>(out, lsum);
}

// Round 6
// 136.602 us; speedup vs baseline: 2.8790x; 1.1092x over previous
//
#include <hip/hip_runtime.h>
#include <hip/hip_bf16.h>
#include <cstdint>

#define N_NODES 4096
#define F_IN    512
#define F_OUT   64
#define H_HEADS 8
#define JC      2          // j-sweep chunks for k_attn_mfma

constexpr float L2E = 1.44269504088896f;

typedef _Float16 half4_t __attribute__((ext_vector_type(4)));
typedef _Float16 half8_t __attribute__((ext_vector_type(8)));
typedef float    f32x4   __attribute__((ext_vector_type(4)));

__device__ inline float fast_exp2(float a) {
#if __has_builtin(__builtin_amdgcn_exp2f)
    return __builtin_amdgcn_exp2f(a);
#else
    return exp2f(a);
#endif
}

// ---------------- K0: adj int32 -> u64 bitmask, row-major + transposed ----------------
__global__ __launch_bounds__(256) void k_adj_bitmask(const int* __restrict__ adj,
                                                     unsigned long long* __restrict__ adjw,
                                                     unsigned long long* __restrict__ adjwT) {
    int lane = threadIdx.x & 63;
    int wid  = (int)((blockIdx.x * blockDim.x + threadIdx.x) >> 6);
    int nwaves = (int)((gridDim.x * blockDim.x) >> 6);
    const int nchunks = N_NODES * (N_NODES / 64);
    for (int cf = wid; cf < nchunks; cf += nwaves) {
        int v = adj[(size_t)cf * 64 + lane];
        unsigned long long mask = __ballot(v > 0);
        if (lane == 0) {
            int i = cf >> 6, c = cf & 63;
            adjw[cf] = mask;                              // [i][c] for k_rowmax
            adjwT[(size_t)c * N_NODES + i] = mask;        // [c][i] for k_attn
        }
    }
}

// ---------------- K0c: pack W -> f16 B-fragments [h][kt(16)][ntile(4)][lane(64)][t(8)] ----------------
// value = W[h][kt*32 + 8*(lane>>4) + t][ntile*16 + (lane&15)]
__global__ __launch_bounds__(256) void k_wpack(const float* __restrict__ W,
                                               _Float16* __restrict__ wfrag) {
    int gid = blockIdx.x * 256 + threadIdx.x;            // 0 .. 8*16*4*64-1
    int h     = gid >> 12;
    int kt    = (gid >> 8) & 15;
    int ntile = (gid >> 6) & 3;
    int lane  = gid & 63;
    int c0 = lane & 15, g = lane >> 4;
    const float* src = W + ((size_t)h * F_IN + kt * 32 + 8 * g) * F_OUT + ntile * 16 + c0;
    half8_t hv;
    #pragma unroll
    for (int t = 0; t < 8; t++) hv[t] = (_Float16)src[(size_t)t * F_OUT];
    *reinterpret_cast<half8_t*>(&wfrag[(size_t)gid * 8]) = hv;
}

// ---------------- K1: Wh = x @ W[h] via MFMA 16x16x32 (x read direct, inline cvt) ----------------
// grid (64, 8), block 256 (4 waves). Wave mt = rt*4+w: rows mt*16..+15, all 64 o, one head.
// Epilogue: scaled scores s_iL/s_jL ( *log2e ) + WhFrag in k_attn's 16x16x32 B-fragment layout:
//   elem (j,o) at h*262144 + ((j>>5)*4 + (o>>4))*512 + ((o&15) + 16*((j&31)>>3))*8 + (j&7)
__global__ __launch_bounds__(256) void k_wh_mfma(const float* __restrict__ x,
                                                 const _Float16* __restrict__ wfrag,
                                                 const float* __restrict__ a_src,
                                                 const float* __restrict__ a_tgt,
                                                 _Float16* __restrict__ WhFrag,
                                                 float* __restrict__ s_iL,
                                                 float* __restrict__ s_jL) {
    const int h    = blockIdx.y;
    const int rt   = blockIdx.x;
    const int t    = threadIdx.x;
    const int lane = t & 63;
    const int w    = t >> 6;
    const int mt   = rt * 4 + w;            // 16-row m-tile index (0..255)
    const int c0   = lane & 15;
    const int gl   = lane >> 4;

    f32x4 acc0 = {0.f, 0.f, 0.f, 0.f};
    f32x4 acc1 = {0.f, 0.f, 0.f, 0.f};
    f32x4 acc2 = {0.f, 0.f, 0.f, 0.f};
    f32x4 acc3 = {0.f, 0.f, 0.f, 0.f};

    const float* __restrict__ xr = x + (size_t)(mt * 16 + c0) * F_IN + 8 * gl;
    const _Float16* __restrict__ Bf = wfrag + (size_t)h * (16 * 4 * 512) + (size_t)lane * 8;

    #pragma unroll
    for (int kt = 0; kt < 16; kt++) {
        float4 v0 = *reinterpret_cast<const float4*>(xr + kt * 32);
        float4 v1 = *reinterpret_cast<const float4*>(xr + kt * 32 + 4);
        half8_t a;
        a[0] = (_Float16)v0.x; a[1] = (_Float16)v0.y; a[2] = (_Float16)v0.z; a[3] = (_Float16)v0.w;
        a[4] = (_Float16)v1.x; a[5] = (_Float16)v1.y; a[6] = (_Float16)v1.z; a[7] = (_Float16)v1.w;
        const _Float16* Bk = Bf + (size_t)kt * 2048;
        half8_t b0 = *reinterpret_cast<const half8_t*>(Bk);
        half8_t b1 = *reinterpret_cast<const half8_t*>(Bk + 512);
        half8_t b2 = *reinterpret_cast<const half8_t*>(Bk + 1024);
        half8_t b3 = *reinterpret_cast<const half8_t*>(Bk + 1536);
        acc0 = __builtin_amdgcn_mfma_f32_16x16x32_f16(a, b0, acc0, 0, 0, 0);
        acc1 = __builtin_amdgcn_mfma_f32_16x16x32_f16(a, b1, acc1, 0, 0, 0);
        acc2 = __builtin_amdgcn_mfma_f32_16x16x32_f16(a, b2, acc2, 0, 0, 0);
        acc3 = __builtin_amdgcn_mfma_f32_16x16x32_f16(a, b3, acc3, 0, 0, 0);
    }

    // scores (f32, scaled by log2e)
    const float as0 = a_src[h * 64 + c0],      at0 = a_tgt[h * 64 + c0];
    const float as1 = a_src[h * 64 + 16 + c0], at1 = a_tgt[h * 64 + 16 + c0];
    const float as2 = a_src[h * 64 + 32 + c0], at2 = a_tgt[h * 64 + 32 + c0];
    const float as3 = a_src[h * 64 + 48 + c0], at3 = a_tgt[h * 64 + 48 + c0];

    #pragma unroll
    for (int reg = 0; reg < 4; reg++) {
        float vi = acc0[reg] * as0 + acc1[reg] * as1 + acc2[reg] * as2 + acc3[reg] * as3;
        float vj = acc0[reg] * at0 + acc1[reg] * at1 + acc2[reg] * at2 + acc3[reg] * at3;
        #pragma unroll
        for (int mm = 8; mm >= 1; mm >>= 1) {
            vi += __shfl_xor(vi, mm, 64);
            vj += __shfl_xor(vj, mm, 64);
        }
        if (c0 == 0) {
            int row = mt * 16 + 4 * gl + reg;
            s_iL[h * N_NODES + row] = vi * L2E;
            s_jL[h * N_NODES + row] = vj * L2E;
        }
    }

    // WhFrag fragment write: j = mt*16 + 4*gl + reg, o = ot*16 + c0
    const int cc    = mt >> 2;
    const int kb    = (mt >> 1) & 1;
    const int lanep = c0 + 16 * ((mt & 1) * 2 + (gl >> 1));
    const int tb    = 4 * (gl & 1);
    _Float16* dst = WhFrag + (size_t)h * (N_NODES * 64)
                  + (size_t)(cc * 2 + kb) * 2048 + (size_t)lanep * 8 + tb;
    f32x4 accs[4] = {acc0, acc1, acc2, acc3};
    #pragma unroll
    for (int ot = 0; ot < 4; ot++) {
        half4_t hv;
        #pragma unroll
        for (int reg = 0; reg < 4; reg++) hv[reg] = (_Float16)accs[ot][reg];
        *reinterpret_cast<half4_t*>(dst + ot * 512) = hv;
    }
}

// ---------------- K2: per (h,i) rowmax (scaled domain) -> negmp, 4 rows per wave ----------------
__global__ __launch_bounds__(256) void k_rowmax(const float* __restrict__ s_iL,
                                                const float* __restrict__ s_jL,
                                                const unsigned long long* __restrict__ adjw,
                                                float* __restrict__ negmp) {
    const int lane = threadIdx.x & 63;
    const int wv   = (int)((blockIdx.x * blockDim.x + threadIdx.x) >> 6);
    const int i0   = wv * 4;

    float mx[4][H_HEADS];
    #pragma unroll
    for (int ii = 0; ii < 4; ii++)
        #pragma unroll
        for (int h = 0; h < H_HEADS; h++) mx[ii][h] = -INFINITY;

    for (int c = 0; c < N_NODES / 64; c++) {
        unsigned long long wd[4];
        #pragma unroll
        for (int ii = 0; ii < 4; ii++) wd[ii] = adjw[(size_t)(i0 + ii) * 64 + c];
        float pen[4];
        #pragma unroll
        for (int ii = 0; ii < 4; ii++) pen[ii] = ((wd[ii] >> lane) & 1ull) ? 0.0f : -INFINITY;
        #pragma unroll
        for (int h = 0; h < H_HEADS; h++) {
            float sj = s_jL[h * N_NODES + c * 64 + lane];
            #pragma unroll
            for (int ii = 0; ii < 4; ii++)
                mx[ii][h] = fmaxf(mx[ii][h], sj + pen[ii]);
        }
    }
    #pragma unroll
    for (int ii = 0; ii < 4; ii++)
        #pragma unroll
        for (int h = 0; h < H_HEADS; h++) {
            float v = mx[ii][h];
            #pragma unroll
            for (int mm = 32; mm >= 1; mm >>= 1) v = fmaxf(v, __shfl_xor(v, mm, 64));
            mx[ii][h] = v;
        }
    if (lane == 0) {
        #pragma unroll
        for (int ii = 0; ii < 4; ii++)
            #pragma unroll
            for (int h = 0; h < H_HEADS; h++) {
                float es = s_iL[h * N_NODES + i0 + ii] + mx[ii][h];   // scaled e at row max
                es = fmaxf(es, 0.2f * es);                            // lrelu commutes with *L2E
                negmp[h * N_NODES + i0 + ii] = -es;
            }
    }
}

// ---------------- K3: P formation + PV via mfma 16x16x32, ones-MFMA denominator, no atomics ----------------
// grid (64, 8, JC), block 256 (4 waves). Wave: 16 rows x 64 o, j-chunk of 2048.
__global__ __launch_bounds__(256) void k_attn_mfma(const _Float16* __restrict__ WhFrag,
                                                   const float* __restrict__ s_iL,
                                                   const float* __restrict__ negmp,
                                                   const float* __restrict__ s_jL,
                                                   const unsigned long long* __restrict__ adjwT,
                                                   float* __restrict__ out0,   // jc=0 partial (= d_out)
                                                   float* __restrict__ out1,   // jc=1 partial (ws)
                                                   float* __restrict__ l0,
                                                   float* __restrict__ l1) {
    const int h    = blockIdx.y;
    const int jc   = blockIdx.z;
    const int t    = threadIdx.x;
    const int lane = t & 63;
    const int w    = t >> 6;
    const int i0   = blockIdx.x * 64 + w * 16;
    const int mrow = lane & 15;
    const int gl   = lane >> 4;
    const int gl8  = gl << 3;

    const float nmp = negmp[h * N_NODES + i0 + mrow];
    const float u   = s_iL[h * N_NODES + i0 + mrow] + nmp;   // siL - mL
    const float n8  = 0.8f * nmp;
    const float* __restrict__ sjh = s_jL + h * N_NODES;
    const _Float16* __restrict__ Bl = WhFrag + (size_t)h * (N_NODES * 64) + (size_t)lane * 8;

    half8_t vone;
    #pragma unroll
    for (int q = 0; q < 8; q++) vone[q] = (_Float16)1.0f;

    f32x4 acc0 = {0.f, 0.f, 0.f, 0.f};
    f32x4 acc1 = {0.f, 0.f, 0.f, 0.f};
    f32x4 acc2 = {0.f, 0.f, 0.f, 0.f};
    f32x4 acc3 = {0.f, 0.f, 0.f, 0.f};
    f32x4 accl = {0.f, 0.f, 0.f, 0.f};

    const int NC   = (N_NODES / 64) / JC;   // 32
    const int cbeg = jc * NC;

    #pragma unroll 2
    for (int c = cbeg; c < cbeg + NC; c++) {
        uint2 word = *reinterpret_cast<const uint2*>(&adjwT[(size_t)c * N_NODES + i0 + mrow]);
        #pragma unroll
        for (int kb = 0; kb < 2; kb++) {
            const int jb = c * 64 + kb * 32 + 8 * gl;
            float4 s0 = *reinterpret_cast<const float4*>(&sjh[jb]);
            float4 s1 = *reinterpret_cast<const float4*>(&sjh[jb + 4]);
            unsigned int bm = ((kb ? word.y : word.x) >> gl8) & 0xFFu;

            float p[8];
            #pragma unroll
            for (int tt = 0; tt < 8; tt++) {
                float sj = (tt == 0) ? s0.x : (tt == 1) ? s0.y : (tt == 2) ? s0.z : (tt == 3) ? s0.w
                         : (tt == 4) ? s1.x : (tt == 5) ? s1.y : (tt == 6) ? s1.z : s1.w;
                float a1  = u + sj;                       // (siL + sjL) - mL
                float a2  = fmaf(0.2f, a1, n8);           // 0.2*(siL+sjL) - mL
                float arg = fmaxf(a1, a2);                // scaled lrelu minus max
                arg = (bm & (1u << tt)) ? arg : -1000.0f; // adjacency mask
                p[tt] = fast_exp2(arg);
            }
            half8_t af;
            #pragma unroll
            for (int tt = 0; tt < 8; tt++) af[tt] = (_Float16)p[tt];

            const _Float16* Bk = Bl + (size_t)(c * 2 + kb) * 2048;
            half8_t b0 = *reinterpret_cast<const half8_t*>(Bk);
            half8_t b1 = *reinterpret_cast<const half8_t*>(Bk + 512);
            half8_t b2 = *reinterpret_cast<const half8_t*>(Bk + 1024);
            half8_t b3 = *reinterpret_cast<const half8_t*>(Bk + 1536);

            acc0 = __builtin_amdgcn_mfma_f32_16x16x32_f16(af, b0, acc0, 0, 0, 0);
            acc1 = __builtin_amdgcn_mfma_f32_16x16x32_f16(af, b1, acc1, 0, 0, 0);
            acc2 = __builtin_amdgcn_mfma_f32_16x16x32_f16(af, b2, acc2, 0, 0, 0);
            acc3 = __builtin_amdgcn_mfma_f32_16x16x32_f16(af, b3, acc3, 0, 0, 0);
            accl = __builtin_amdgcn_mfma_f32_16x16x32_f16(af, vone, accl, 0, 0, 0);
        }
    }

    float* __restrict__ op = jc ? out1 : out0;
    float* __restrict__ lp = jc ? l1 : l0;

    if (mrow == 0) {
        #pragma unroll
        for (int r = 0; r < 4; r++)
            lp[h * N_NODES + i0 + 4 * gl + r] = accl[r];
    }
    #pragma unroll
    for (int r = 0; r < 4; r++) {
        int row   = i0 + 4 * gl + r;
        size_t ob = ((size_t)h * N_NODES + row) * 64 + mrow;
        op[ob + 0]  = acc0[r];
        op[ob + 16] = acc1[r];
        op[ob + 32] = acc2[r];
        op[ob + 48] = acc3[r];
    }
}

// ---------------- K4: out = (out + part1) / (l0 + l1) ----------------
__global__ __launch_bounds__(256) void k_norm(float* __restrict__ out,
                                              const float* __restrict__ part1,
                                              const float* __restrict__ l0,
                                              const float* __restrict__ l1) {
    int idx = blockIdx.x * 256 + threadIdx.x;        // float4 index
    int row = idx >> 4;
    float inv = 1.0f / (l0[row] + l1[row]);
    float4 a = reinterpret_cast<const float4*>(out)[idx];
    float4 b = reinterpret_cast<const float4*>(part1)[idx];
    float4 v;
    v.x = (a.x + b.x) * inv;
    v.y = (a.y + b.y) * inv;
    v.z = (a.z + b.z) * inv;
    v.w = (a.w + b.w) * inv;
    reinterpret_cast<float4*>(out)[idx] = v;
}

// ---------------- launch ----------------
extern "C" void kernel_launch(void* const* d_in, const int* in_sizes, int n_in,
                              void* d_out, int out_size, void* d_ws, size_t ws_size,
                              hipStream_t stream) {
    const float* x     = (const float*)d_in[0];
    const int*   adj   = (const int*)d_in[1];
    const float* W     = (const float*)d_in[2];
    const float* a_src = (const float*)d_in[3];
    const float* a_tgt = (const float*)d_in[4];
    float* out = (float*)d_out;

    char* ws = (char*)d_ws;
    _Float16* WhFrag = (_Float16*)(ws);                               // 4 MB
    _Float16* wfrag  = (_Float16*)(ws + 4194304);                     // 512 KB
    float* s_iL      = (float*)(ws + 4718592);                        // 128 KB
    float* s_jL      = (float*)(ws + 4849664);                        // 128 KB
    float* negmp     = (float*)(ws + 4980736);                        // 128 KB
    float* l0        = (float*)(ws + 5111808);                        // 128 KB
    float* l1        = (float*)(ws + 5242880);                        // 128 KB
    float* part1     = (float*)(ws + 5373952);                        // 8 MB
    unsigned long long* adjw  = (unsigned long long*)(ws + 13762560); // 2 MB [i][c]
    unsigned long long* adjwT = (unsigned long long*)(ws + 15859712); // 2 MB [c][i]

    k_adj_bitmask<<<2048, 256, 0, stream>>>(adj, adjw, adjwT);
    k_wpack<<<128, 256, 0, stream>>>(W, wfrag);
    k_wh_mfma<<<dim3(N_NODES / 64, H_HEADS), 256, 0, stream>>>(x, wfrag, a_src, a_tgt, WhFrag, s_iL, s_jL);
    k_rowmax<<<256, 256, 0, stream>>>(s_iL, s_jL, adjw, negmp);
    k_attn_mfma<<<dim3(N_NODES / 64, H_HEADS, JC), 256, 0, stream>>>(WhFrag, s_iL, negmp, s_jL, adjwT,
                                                                     out, part1, l0, l1);
    k_norm<<<(H_HEADS * N_NODES * F_OUT / 4) / 256, 256, 0, stream>>>(out, part1, l0, l1);
}

// Round 8
// 118.838 us; speedup vs baseline: 3.3093x; 1.1495x over previous
//
#include <hip/hip_runtime.h>
#include <hip/hip_fp16.h>
#include <cstdint>

#define N_NODES 4096
#define F_IN    512
#define F_OUT   64
#define H_HEADS 8
#define JC      4          // j-sweep chunks for k_attn_mfma

constexpr float L2E = 1.44269504088896f;

typedef _Float16 half2_t __attribute__((ext_vector_type(2)));
typedef _Float16 half4_t __attribute__((ext_vector_type(4)));
typedef _Float16 half8_t __attribute__((ext_vector_type(8)));
typedef float    f32x4   __attribute__((ext_vector_type(4)));

__device__ inline half2_t exp2_pk(half2_t v) {
    __half2 h = __builtin_bit_cast(__half2, v);
    h = h2exp2(h);
    return __builtin_bit_cast(half2_t, h);
}

// ---------------- K0: merged W-pack (blocks 0..127) + adj bitmask (blocks 128..2175) ----------------
// wfrag: [h][kt(16)][ntile(4)][lane(64)][t(8)], value = W[h][kt*32+8*(lane>>4)+t][ntile*16+(lane&15)]
__global__ __launch_bounds__(256) void k_prep(const int* __restrict__ adj,
                                              const float* __restrict__ W,
                                              unsigned long long* __restrict__ adjw,
                                              unsigned long long* __restrict__ adjwT,
                                              _Float16* __restrict__ wfrag) {
    if (blockIdx.x < 128) {
        int gid = blockIdx.x * 256 + threadIdx.x;         // 0 .. 32767
        int h     = gid >> 12;
        int kt    = (gid >> 8) & 15;
        int ntile = (gid >> 6) & 3;
        int lane  = gid & 63;
        int c0 = lane & 15, g = lane >> 4;
        const float* src = W + ((size_t)h * F_IN + kt * 32 + 8 * g) * F_OUT + ntile * 16 + c0;
        half8_t hv;
        #pragma unroll
        for (int t = 0; t < 8; t++) hv[t] = (_Float16)src[(size_t)t * F_OUT];
        *reinterpret_cast<half8_t*>(&wfrag[(size_t)gid * 8]) = hv;
        return;
    }
    int bid  = blockIdx.x - 128;                          // 0..2047
    int lane = threadIdx.x & 63;
    int wid  = (int)((bid * 256 + threadIdx.x) >> 6);
    int nwaves = (2048 * 256) >> 6;
    const int nchunks = N_NODES * (N_NODES / 64);
    for (int cf = wid; cf < nchunks; cf += nwaves) {
        int v = adj[(size_t)cf * 64 + lane];
        unsigned long long mask = __ballot(v > 0);
        if (lane == 0) {
            int i = cf >> 6, c = cf & 63;
            adjw[cf] = mask;                              // [i][c] for k_rowmax
            adjwT[(size_t)c * N_NODES + i] = mask;        // [c][i] for k_attn
        }
    }
}

// ---------------- K1: Wh = x @ W[h] via MFMA 16x16x32, K-split x2 + LDS reduce ----------------
// grid (64, 8), block 512 (8 waves): wave w -> mtw = w&3, kh = w>>2. mt = rt*4 + mtw.
__global__ __launch_bounds__(512) void k_wh_mfma(const float* __restrict__ x,
                                                 const _Float16* __restrict__ wfrag,
                                                 const float* __restrict__ a_src,
                                                 const float* __restrict__ a_tgt,
                                                 _Float16* __restrict__ WhFrag,
                                                 float* __restrict__ s_iL,
                                                 float* __restrict__ s_jL,
                                                 _Float16* __restrict__ s_jLh) {
    __shared__ f32x4 red[4][4][64];                       // 16 KB
    const int h    = blockIdx.y;
    const int rt   = blockIdx.x;
    const int t    = threadIdx.x;
    const int lane = t & 63;
    const int w    = t >> 6;
    const int mtw  = w & 3;
    const int kh   = w >> 2;
    const int mt   = rt * 4 + mtw;          // 16-row m-tile index (0..255)
    const int c0   = lane & 15;
    const int gl   = lane >> 4;

    f32x4 acc0 = {0.f, 0.f, 0.f, 0.f};
    f32x4 acc1 = {0.f, 0.f, 0.f, 0.f};
    f32x4 acc2 = {0.f, 0.f, 0.f, 0.f};
    f32x4 acc3 = {0.f, 0.f, 0.f, 0.f};

    const float* __restrict__ xr = x + (size_t)(mt * 16 + c0) * F_IN + 8 * gl + kh * 256;
    const _Float16* __restrict__ Bf = wfrag + (size_t)h * (16 * 4 * 512)
                                    + (size_t)kh * 8 * 2048 + (size_t)lane * 8;

    #pragma unroll
    for (int kt = 0; kt < 8; kt++) {
        float4 v0 = *reinterpret_cast<const float4*>(xr + kt * 32);
        float4 v1 = *reinterpret_cast<const float4*>(xr + kt * 32 + 4);
        half8_t a;
        a[0] = (_Float16)v0.x; a[1] = (_Float16)v0.y; a[2] = (_Float16)v0.z; a[3] = (_Float16)v0.w;
        a[4] = (_Float16)v1.x; a[5] = (_Float16)v1.y; a[6] = (_Float16)v1.z; a[7] = (_Float16)v1.w;
        const _Float16* Bk = Bf + (size_t)kt * 2048;
        half8_t b0 = *reinterpret_cast<const half8_t*>(Bk);
        half8_t b1 = *reinterpret_cast<const half8_t*>(Bk + 512);
        half8_t b2 = *reinterpret_cast<const half8_t*>(Bk + 1024);
        half8_t b3 = *reinterpret_cast<const half8_t*>(Bk + 1536);
        acc0 = __builtin_amdgcn_mfma_f32_16x16x32_f16(a, b0, acc0, 0, 0, 0);
        acc1 = __builtin_amdgcn_mfma_f32_16x16x32_f16(a, b1, acc1, 0, 0, 0);
        acc2 = __builtin_amdgcn_mfma_f32_16x16x32_f16(a, b2, acc2, 0, 0, 0);
        acc3 = __builtin_amdgcn_mfma_f32_16x16x32_f16(a, b3, acc3, 0, 0, 0);
    }

    if (kh == 1) {
        red[mtw][0][lane] = acc0;
        red[mtw][1][lane] = acc1;
        red[mtw][2][lane] = acc2;
        red[mtw][3][lane] = acc3;
    }
    __syncthreads();
    if (kh == 1) return;

    acc0 += red[mtw][0][lane];
    acc1 += red[mtw][1][lane];
    acc2 += red[mtw][2][lane];
    acc3 += red[mtw][3][lane];

    const float as0 = a_src[h * 64 + c0],      at0 = a_tgt[h * 64 + c0];
    const float as1 = a_src[h * 64 + 16 + c0], at1 = a_tgt[h * 64 + 16 + c0];
    const float as2 = a_src[h * 64 + 32 + c0], at2 = a_tgt[h * 64 + 32 + c0];
    const float as3 = a_src[h * 64 + 48 + c0], at3 = a_tgt[h * 64 + 48 + c0];

    #pragma unroll
    for (int reg = 0; reg < 4; reg++) {
        float vi = acc0[reg] * as0 + acc1[reg] * as1 + acc2[reg] * as2 + acc3[reg] * as3;
        float vj = acc0[reg] * at0 + acc1[reg] * at1 + acc2[reg] * at2 + acc3[reg] * at3;
        #pragma unroll
        for (int mm = 8; mm >= 1; mm >>= 1) {
            vi += __shfl_xor(vi, mm, 64);
            vj += __shfl_xor(vj, mm, 64);
        }
        if (c0 == 0) {
            int row = mt * 16 + 4 * gl + reg;
            float sjl = vj * L2E;
            s_iL[h * N_NODES + row]  = vi * L2E;
            s_jL[h * N_NODES + row]  = sjl;
            s_jLh[h * N_NODES + row] = (_Float16)sjl;
        }
    }

    const int cc    = mt >> 2;
    const int kb    = (mt >> 1) & 1;
    const int lanep = c0 + 16 * ((mt & 1) * 2 + (gl >> 1));
    const int tb    = 4 * (gl & 1);
    _Float16* dst = WhFrag + (size_t)h * (N_NODES * 64)
                  + (size_t)(cc * 2 + kb) * 2048 + (size_t)lanep * 8 + tb;
    f32x4 accs[4] = {acc0, acc1, acc2, acc3};
    #pragma unroll
    for (int ot = 0; ot < 4; ot++) {
        half4_t hv;
        #pragma unroll
        for (int reg = 0; reg < 4; reg++) hv[reg] = (_Float16)accs[ot][reg];
        *reinterpret_cast<half4_t*>(dst + ot * 512) = hv;
    }
}

// ---------------- K2: per (h,i) rowmax (scaled domain) -> negmp, 1 row per wave ----------------
__global__ __launch_bounds__(256) void k_rowmax(const float* __restrict__ s_iL,
                                                const float* __restrict__ s_jL,
                                                const unsigned long long* __restrict__ adjw,
                                                float* __restrict__ negmp) {
    const int lane = threadIdx.x & 63;
    const int i    = (int)((blockIdx.x * blockDim.x + threadIdx.x) >> 6);

    float mx[H_HEADS];
    #pragma unroll
    for (int h = 0; h < H_HEADS; h++) mx[h] = -INFINITY;

    for (int c = 0; c < N_NODES / 64; c++) {
        unsigned long long word = adjw[(size_t)i * 64 + c];
        float pen = ((word >> lane) & 1ull) ? 0.0f : -INFINITY;
        #pragma unroll
        for (int h = 0; h < H_HEADS; h++) {
            float sj = s_jL[h * N_NODES + c * 64 + lane];
            mx[h] = fmaxf(mx[h], sj + pen);
        }
    }
    #pragma unroll
    for (int h = 0; h < H_HEADS; h++) {
        float v = mx[h];
        #pragma unroll
        for (int mm = 32; mm >= 1; mm >>= 1) v = fmaxf(v, __shfl_xor(v, mm, 64));
        mx[h] = v;
    }
    if (lane == 0) {
        #pragma unroll
        for (int h = 0; h < H_HEADS; h++) {
            float es = s_iL[h * N_NODES + i] + mx[h];
            es = fmaxf(es, 0.2f * es);
            negmp[h * N_NODES + i] = -es;
        }
    }
}

// ---------------- K3: packed-f16 P formation + PV via mfma 16x16x32 ----------------
__global__ __launch_bounds__(256) void k_attn_mfma(const _Float16* __restrict__ WhFrag,
                                                   const float* __restrict__ s_iL,
                                                   const float* __restrict__ negmp,
                                                   const _Float16* __restrict__ s_jLh,
                                                   const unsigned long long* __restrict__ adjwT,
                                                   float* __restrict__ out0,
                                                   _Float16* __restrict__ partH,
                                                   float* __restrict__ lbuf) {
    __shared__ unsigned int mtab[256][4];   // bm8 -> 4 packed halfword selects (0xFFFF = masked)
    {
        unsigned int bm = threadIdx.x;
        #pragma unroll
        for (int q = 0; q < 4; q++) {
            unsigned int lo = ((bm >> (2 * q)) & 1u) ? 0u : 0xFFFFu;
            unsigned int hi = ((bm >> (2 * q + 1)) & 1u) ? 0u : 0xFFFF0000u;
            mtab[bm][q] = lo | hi;
        }
    }
    __syncthreads();

    const int h    = blockIdx.y;
    const int jc   = blockIdx.z;
    const int lane = threadIdx.x & 63;
    const int w    = threadIdx.x >> 6;
    const int i0   = blockIdx.x * 64 + w * 16;
    const int mrow = lane & 15;
    const int gl   = lane >> 4;
    const int gl8  = gl << 3;

    const float nmp = negmp[h * N_NODES + i0 + mrow];
    const float uf  = s_iL[h * N_NODES + i0 + mrow] + nmp;     // siL - mL
    const _Float16 uh  = (_Float16)uf;
    const _Float16 n8h = (_Float16)(0.8f * nmp);
    const half2_t u2   = {uh, uh};
    const half2_t n82  = {n8h, n8h};
    const half2_t c02  = {(_Float16)0.2f, (_Float16)0.2f};
    const half2_t negk = {(_Float16)(-1000.0f), (_Float16)(-1000.0f)};
    const unsigned int negu = __builtin_bit_cast(unsigned int, negk);

    const _Float16* __restrict__ sjh = s_jLh + h * N_NODES;
    const _Float16* __restrict__ Bl  = WhFrag + (size_t)h * (N_NODES * 64) + (size_t)lane * 8;

    half8_t vone;
    #pragma unroll
    for (int q = 0; q < 8; q++) vone[q] = (_Float16)1.0f;

    f32x4 acc0 = {0.f, 0.f, 0.f, 0.f};
    f32x4 acc1 = {0.f, 0.f, 0.f, 0.f};
    f32x4 acc2 = {0.f, 0.f, 0.f, 0.f};
    f32x4 acc3 = {0.f, 0.f, 0.f, 0.f};
    f32x4 accl = {0.f, 0.f, 0.f, 0.f};

    const int NC   = (N_NODES / 64) / JC;   // 16
    const int cbeg = jc * NC;

    #pragma unroll 2
    for (int c = cbeg; c < cbeg + NC; c++) {
        uint2 word = *reinterpret_cast<const uint2*>(&adjwT[(size_t)c * N_NODES + i0 + mrow]);
        #pragma unroll
        for (int kb = 0; kb < 2; kb++) {
            const int jb = c * 64 + kb * 32 + 8 * gl;
            half8_t sjv = *reinterpret_cast<const half8_t*>(&sjh[jb]);
            unsigned int bm8 = ((kb ? word.y : word.x) >> gl8) & 0xFFu;
            uint4 mk = *reinterpret_cast<const uint4*>(&mtab[bm8][0]);

            half8_t af;
            #pragma unroll
            for (int q = 0; q < 4; q++) {
                half2_t sj2 = {sjv[2 * q], sjv[2 * q + 1]};
                half2_t a1  = u2 + sj2;
                half2_t a2  = a1 * c02 + n82;
                half2_t am  = __builtin_elementwise_max(a1, a2);
                unsigned int au = __builtin_bit_cast(unsigned int, am);
                unsigned int mq = (q == 0) ? mk.x : (q == 1) ? mk.y : (q == 2) ? mk.z : mk.w;
                unsigned int su = (mq & negu) | (~mq & au);
                half2_t p = exp2_pk(__builtin_bit_cast(half2_t, su));
                af[2 * q]     = p[0];
                af[2 * q + 1] = p[1];
            }

            const _Float16* Bk = Bl + (size_t)(c * 2 + kb) * 2048;
            half8_t b0 = *reinterpret_cast<const half8_t*>(Bk);
            half8_t b1 = *reinterpret_cast<const half8_t*>(Bk + 512);
            half8_t b2 = *reinterpret_cast<const half8_t*>(Bk + 1024);
            half8_t b3 = *reinterpret_cast<const half8_t*>(Bk + 1536);

            acc0 = __builtin_amdgcn_mfma_f32_16x16x32_f16(af, b0, acc0, 0, 0, 0);
            acc1 = __builtin_amdgcn_mfma_f32_16x16x32_f16(af, b1, acc1, 0, 0, 0);
            acc2 = __builtin_amdgcn_mfma_f32_16x16x32_f16(af, b2, acc2, 0, 0, 0);
            acc3 = __builtin_amdgcn_mfma_f32_16x16x32_f16(af, b3, acc3, 0, 0, 0);
            accl = __builtin_amdgcn_mfma_f32_16x16x32_f16(af, vone, accl, 0, 0, 0);
        }
    }

    float* lp = lbuf + (size_t)jc * (H_HEADS * N_NODES);
    if (mrow == 0) {
        #pragma unroll
        for (int r = 0; r < 4; r++)
            lp[h * N_NODES + i0 + 4 * gl + r] = accl[r];
    }
    if (jc == 0) {
        #pragma unroll
        for (int r = 0; r < 4; r++) {
            int row   = i0 + 4 * gl + r;
            size_t ob = ((size_t)h * N_NODES + row) * 64 + mrow;
            out0[ob + 0]  = acc0[r];
            out0[ob + 16] = acc1[r];
            out0[ob + 32] = acc2[r];
            out0[ob + 48] = acc3[r];
        }
    } else {
        _Float16* op = partH + (size_t)(jc - 1) * ((size_t)H_HEADS * N_NODES * F_OUT);
        #pragma unroll
        for (int r = 0; r < 4; r++) {
            int row   = i0 + 4 * gl + r;
            size_t ob = ((size_t)h * N_NODES + row) * 64 + mrow;
            op[ob + 0]  = (_Float16)acc0[r];
            op[ob + 16] = (_Float16)acc1[r];
            op[ob + 32] = (_Float16)acc2[r];
            op[ob + 48] = (_Float16)acc3[r];
        }
    }
}

// ---------------- K4: out = (out + sum f16 partials) / sum l ----------------
__global__ __launch_bounds__(256) void k_norm(float* __restrict__ out,
                                              const _Float16* __restrict__ partH,
                                              const float* __restrict__ lbuf) {
    const int HN = H_HEADS * N_NODES;
    int idx = blockIdx.x * 256 + threadIdx.x;        // float4 index
    int row = idx >> 4;
    float inv = 1.0f / (lbuf[row] + lbuf[HN + row] + lbuf[2 * HN + row] + lbuf[3 * HN + row]);
    float4 a = reinterpret_cast<const float4*>(out)[idx];
    float s0 = a.x, s1 = a.y, s2 = a.z, s3 = a.w;
    #pragma unroll
    for (int p = 0; p < 3; p++) {
        half4_t hp = *reinterpret_cast<const half4_t*>(
            &partH[(size_t)p * ((size_t)H_HEADS * N_NODES * F_OUT) + (size_t)idx * 4]);
        s0 += (float)hp[0]; s1 += (float)hp[1]; s2 += (float)hp[2]; s3 += (float)hp[3];
    }
    float4 v = {s0 * inv, s1 * inv, s2 * inv, s3 * inv};
    reinterpret_cast<float4*>(out)[idx] = v;
}

// ---------------- launch ----------------
extern "C" void kernel_launch(void* const* d_in, const int* in_sizes, int n_in,
                              void* d_out, int out_size, void* d_ws, size_t ws_size,
                              hipStream_t stream) {
    const float* x     = (const float*)d_in[0];
    const int*   adj   = (const int*)d_in[1];
    const float* W     = (const float*)d_in[2];
    const float* a_src = (const float*)d_in[3];
    const float* a_tgt = (const float*)d_in[4];
    float* out = (float*)d_out;

    // Workspace layout via accumulating allocator (R7's hand-computed offsets overlapped:
    // negmp/lbuf and lbuf/partH and partH/adjw collided -> race -> NaN).
    char* ws = (char*)d_ws;
    size_t off = 0;
    auto alloc = [&](size_t bytes) -> char* {
        char* p = ws + off;
        off += (bytes + 255) & ~(size_t)255;
        return p;
    };
    _Float16* WhFrag = (_Float16*)alloc((size_t)H_HEADS * N_NODES * F_OUT * 2);        // 4 MB
    _Float16* wfrag  = (_Float16*)alloc((size_t)H_HEADS * 16 * 4 * 64 * 8 * 2);        // 512 KB
    float* s_iL      = (float*)alloc((size_t)H_HEADS * N_NODES * 4);                   // 128 KB
    float* s_jL      = (float*)alloc((size_t)H_HEADS * N_NODES * 4);                   // 128 KB
    _Float16* s_jLh  = (_Float16*)alloc((size_t)H_HEADS * N_NODES * 2);                // 64 KB
    float* negmp     = (float*)alloc((size_t)H_HEADS * N_NODES * 4);                   // 128 KB
    float* lbuf      = (float*)alloc((size_t)JC * H_HEADS * N_NODES * 4);              // 512 KB
    _Float16* partH  = (_Float16*)alloc((size_t)(JC - 1) * H_HEADS * N_NODES * F_OUT * 2); // 12 MB
    unsigned long long* adjw  = (unsigned long long*)alloc((size_t)N_NODES * (N_NODES / 64) * 8); // 2 MB
    unsigned long long* adjwT = (unsigned long long*)alloc((size_t)N_NODES * (N_NODES / 64) * 8); // 2 MB
    (void)ws_size;

    k_prep<<<2176, 256, 0, stream>>>(adj, W, adjw, adjwT, wfrag);
    k_wh_mfma<<<dim3(N_NODES / 64, H_HEADS), 512, 0, stream>>>(x, wfrag, a_src, a_tgt,
                                                               WhFrag, s_iL, s_jL, s_jLh);
    k_rowmax<<<1024, 256, 0, stream>>>(s_iL, s_jL, adjw, negmp);
    k_attn_mfma<<<dim3(N_NODES / 64, H_HEADS, JC), 256, 0, stream>>>(WhFrag, s_iL, negmp, s_jLh,
                                                                     adjwT, out, partH, lbuf);
    k_norm<<<(H_HEADS * N_NODES * F_OUT / 4) / 256, 256, 0, stream>>>(out, partH, lbuf);
}

// Round 9
// 96.750 us; speedup vs baseline: 4.0649x; 1.2283x over previous
//
#include <hip/hip_runtime.h>
#include <hip/hip_fp16.h>
#include <cstdint>

#define N_NODES 4096
#define F_IN    512
#define F_OUT   64
#define H_HEADS 8
#define JC      4          // j-sweep chunks for k_attn_mfma

constexpr float L2E = 1.44269504088896f;

typedef _Float16 half2_t __attribute__((ext_vector_type(2)));
typedef _Float16 half4_t __attribute__((ext_vector_type(4)));
typedef _Float16 half8_t __attribute__((ext_vector_type(8)));
typedef float    f32x4   __attribute__((ext_vector_type(4)));

__device__ inline unsigned int exp2_pk_u(unsigned int au) {
    __half2 h = __builtin_bit_cast(__half2, au);
    h = h2exp2(h);
    return __builtin_bit_cast(unsigned int, h);
}

// ---------------- K0: merged W-pack (blocks 0..127) + adj bitmask -> adjwT (blocks 128..2175) ----------------
// wfrag: [h][kt(16)][ntile(4)][lane(64)][t(8)], value = W[h][kt*32+8*(lane>>4)+t][ntile*16+(lane&15)]
__global__ __launch_bounds__(256) void k_prep(const int* __restrict__ adj,
                                              const float* __restrict__ W,
                                              unsigned long long* __restrict__ adjwT,
                                              _Float16* __restrict__ wfrag) {
    if (blockIdx.x < 128) {
        int gid = blockIdx.x * 256 + threadIdx.x;         // 0 .. 32767
        int h     = gid >> 12;
        int kt    = (gid >> 8) & 15;
        int ntile = (gid >> 6) & 3;
        int lane  = gid & 63;
        int c0 = lane & 15, g = lane >> 4;
        const float* src = W + ((size_t)h * F_IN + kt * 32 + 8 * g) * F_OUT + ntile * 16 + c0;
        half8_t hv;
        #pragma unroll
        for (int t = 0; t < 8; t++) hv[t] = (_Float16)src[(size_t)t * F_OUT];
        *reinterpret_cast<half8_t*>(&wfrag[(size_t)gid * 8]) = hv;
        return;
    }
    int bid  = blockIdx.x - 128;                          // 0..2047
    int lane = threadIdx.x & 63;
    int wid  = (int)((bid * 256 + threadIdx.x) >> 6);
    int nwaves = (2048 * 256) >> 6;
    const int nchunks = N_NODES * (N_NODES / 64);
    for (int cf = wid; cf < nchunks; cf += nwaves) {
        int v = adj[(size_t)cf * 64 + lane];
        unsigned long long mask = __ballot(v > 0);
        if (lane == 0) {
            int i = cf >> 6, c = cf & 63;
            adjwT[(size_t)c * N_NODES + i] = mask;        // [c][i] for k_attn
        }
    }
}

// ---------------- K1: Wh = x @ W[h] via MFMA 16x16x32, K-split x2 + LDS reduce ----------------
// grid (64, 8), block 512 (8 waves): wave w -> mtw = w&3, kh = w>>2. mt = rt*4 + mtw.
__global__ __launch_bounds__(512) void k_wh_mfma(const float* __restrict__ x,
                                                 const _Float16* __restrict__ wfrag,
                                                 const float* __restrict__ a_src,
                                                 const float* __restrict__ a_tgt,
                                                 _Float16* __restrict__ WhFrag,
                                                 float* __restrict__ s_iL,
                                                 _Float16* __restrict__ s_jLh) {
    __shared__ f32x4 red[4][4][64];                       // 16 KB
    const int h    = blockIdx.y;
    const int rt   = blockIdx.x;
    const int t    = threadIdx.x;
    const int lane = t & 63;
    const int w    = t >> 6;
    const int mtw  = w & 3;
    const int kh   = w >> 2;
    const int mt   = rt * 4 + mtw;          // 16-row m-tile index (0..255)
    const int c0   = lane & 15;
    const int gl   = lane >> 4;

    f32x4 acc0 = {0.f, 0.f, 0.f, 0.f};
    f32x4 acc1 = {0.f, 0.f, 0.f, 0.f};
    f32x4 acc2 = {0.f, 0.f, 0.f, 0.f};
    f32x4 acc3 = {0.f, 0.f, 0.f, 0.f};

    const float* __restrict__ xr = x + (size_t)(mt * 16 + c0) * F_IN + 8 * gl + kh * 256;
    const _Float16* __restrict__ Bf = wfrag + (size_t)h * (16 * 4 * 512)
                                    + (size_t)kh * 8 * 2048 + (size_t)lane * 8;

    #pragma unroll
    for (int kt = 0; kt < 8; kt++) {
        float4 v0 = *reinterpret_cast<const float4*>(xr + kt * 32);
        float4 v1 = *reinterpret_cast<const float4*>(xr + kt * 32 + 4);
        half8_t a;
        a[0] = (_Float16)v0.x; a[1] = (_Float16)v0.y; a[2] = (_Float16)v0.z; a[3] = (_Float16)v0.w;
        a[4] = (_Float16)v1.x; a[5] = (_Float16)v1.y; a[6] = (_Float16)v1.z; a[7] = (_Float16)v1.w;
        const _Float16* Bk = Bf + (size_t)kt * 2048;
        half8_t b0 = *reinterpret_cast<const half8_t*>(Bk);
        half8_t b1 = *reinterpret_cast<const half8_t*>(Bk + 512);
        half8_t b2 = *reinterpret_cast<const half8_t*>(Bk + 1024);
        half8_t b3 = *reinterpret_cast<const half8_t*>(Bk + 1536);
        acc0 = __builtin_amdgcn_mfma_f32_16x16x32_f16(a, b0, acc0, 0, 0, 0);
        acc1 = __builtin_amdgcn_mfma_f32_16x16x32_f16(a, b1, acc1, 0, 0, 0);
        acc2 = __builtin_amdgcn_mfma_f32_16x16x32_f16(a, b2, acc2, 0, 0, 0);
        acc3 = __builtin_amdgcn_mfma_f32_16x16x32_f16(a, b3, acc3, 0, 0, 0);
    }

    if (kh == 1) {
        red[mtw][0][lane] = acc0;
        red[mtw][1][lane] = acc1;
        red[mtw][2][lane] = acc2;
        red[mtw][3][lane] = acc3;
    }
    __syncthreads();
    if (kh == 1) return;

    acc0 += red[mtw][0][lane];
    acc1 += red[mtw][1][lane];
    acc2 += red[mtw][2][lane];
    acc3 += red[mtw][3][lane];

    const float as0 = a_src[h * 64 + c0],      at0 = a_tgt[h * 64 + c0];
    const float as1 = a_src[h * 64 + 16 + c0], at1 = a_tgt[h * 64 + 16 + c0];
    const float as2 = a_src[h * 64 + 32 + c0], at2 = a_tgt[h * 64 + 32 + c0];
    const float as3 = a_src[h * 64 + 48 + c0], at3 = a_tgt[h * 64 + 48 + c0];

    #pragma unroll
    for (int reg = 0; reg < 4; reg++) {
        float vi = acc0[reg] * as0 + acc1[reg] * as1 + acc2[reg] * as2 + acc3[reg] * as3;
        float vj = acc0[reg] * at0 + acc1[reg] * at1 + acc2[reg] * at2 + acc3[reg] * at3;
        #pragma unroll
        for (int mm = 8; mm >= 1; mm >>= 1) {
            vi += __shfl_xor(vi, mm, 64);
            vj += __shfl_xor(vj, mm, 64);
        }
        if (c0 == 0) {
            int row = mt * 16 + 4 * gl + reg;
            s_iL[h * N_NODES + row]  = vi * L2E;
            s_jLh[h * N_NODES + row] = (_Float16)(vj * L2E);
        }
    }

    const int cc    = mt >> 2;
    const int kb    = (mt >> 1) & 1;
    const int lanep = c0 + 16 * ((mt & 1) * 2 + (gl >> 1));
    const int tb    = 4 * (gl & 1);
    _Float16* dst = WhFrag + (size_t)h * (N_NODES * 64)
                  + (size_t)(cc * 2 + kb) * 2048 + (size_t)lanep * 8 + tb;
    f32x4 accs[4] = {acc0, acc1, acc2, acc3};
    #pragma unroll
    for (int ot = 0; ot < 4; ot++) {
        half4_t hv;
        #pragma unroll
        for (int reg = 0; reg < 4; reg++) hv[reg] = (_Float16)accs[ot][reg];
        *reinterpret_cast<half4_t*>(dst + ot * 512) = hv;
    }
}

// ---------------- K2: per-head global max of s_jLh (softmax shift; adjacency-free, see theory) ----------------
__global__ __launch_bounds__(256) void k_hmax(const _Float16* __restrict__ s_jLh,
                                              float* __restrict__ mxAll) {
    __shared__ float red[4];
    const int h = blockIdx.x;
    const int t = threadIdx.x;
    const _Float16* p = s_jLh + h * N_NODES;
    float m = -INFINITY;
    for (int k = t; k < N_NODES; k += 256) m = fmaxf(m, (float)p[k]);
    #pragma unroll
    for (int mm = 32; mm >= 1; mm >>= 1) m = fmaxf(m, __shfl_xor(m, mm, 64));
    if ((t & 63) == 0) red[t >> 6] = m;
    __syncthreads();
    if (t == 0) mxAll[h] = fmaxf(fmaxf(red[0], red[1]), fmaxf(red[2], red[3]));
}

// ---------------- K3: packed-f16 P formation (AND-mask after exp) + PV via mfma 16x16x32 ----------------
__global__ __launch_bounds__(256) void k_attn_mfma(const _Float16* __restrict__ WhFrag,
                                                   const float* __restrict__ s_iL,
                                                   const float* __restrict__ mxAll,
                                                   const _Float16* __restrict__ s_jLh,
                                                   const unsigned long long* __restrict__ adjwT,
                                                   float* __restrict__ out0,
                                                   _Float16* __restrict__ partH,
                                                   float* __restrict__ lbuf) {
    __shared__ unsigned int ktab[256][4];   // bm8 -> 4 packed halfword KEEP masks (0xFFFF = neighbor)
    {
        unsigned int bm = threadIdx.x;
        #pragma unroll
        for (int q = 0; q < 4; q++) {
            unsigned int lo = ((bm >> (2 * q)) & 1u) ? 0xFFFFu : 0u;
            unsigned int hi = ((bm >> (2 * q + 1)) & 1u) ? 0xFFFF0000u : 0u;
            ktab[bm][q] = lo | hi;
        }
    }
    __syncthreads();

    const int h    = blockIdx.y;
    const int jc   = blockIdx.z;
    const int lane = threadIdx.x & 63;
    const int w    = threadIdx.x >> 6;
    const int i0   = blockIdx.x * 64 + w * 16;
    const int mrow = lane & 15;
    const int gl   = lane >> 4;
    const int gl8  = gl << 3;

    const float siL = s_iL[h * N_NODES + i0 + mrow];
    const float tmx = siL + mxAll[h];
    const float m   = fmaxf(tmx, 0.2f * tmx);          // row shift (>= true masked max)
    const _Float16 uh  = (_Float16)(siL - m);
    const _Float16 n8h = (_Float16)(-0.8f * m);
    half8_t u8, n88, c028;
    #pragma unroll
    for (int q = 0; q < 8; q++) { u8[q] = uh; n88[q] = n8h; c028[q] = (_Float16)0.2f; }

    const _Float16* __restrict__ sjh = s_jLh + h * N_NODES;
    const _Float16* __restrict__ Bl  = WhFrag + (size_t)h * (N_NODES * 64) + (size_t)lane * 8;

    half8_t vone;
    #pragma unroll
    for (int q = 0; q < 8; q++) vone[q] = (_Float16)1.0f;

    f32x4 acc0 = {0.f, 0.f, 0.f, 0.f};
    f32x4 acc1 = {0.f, 0.f, 0.f, 0.f};
    f32x4 acc2 = {0.f, 0.f, 0.f, 0.f};
    f32x4 acc3 = {0.f, 0.f, 0.f, 0.f};
    f32x4 accl = {0.f, 0.f, 0.f, 0.f};

    const int NC   = (N_NODES / 64) / JC;   // 16
    const int cbeg = jc * NC;

    #pragma unroll 2
    for (int c = cbeg; c < cbeg + NC; c++) {
        uint2 word = *reinterpret_cast<const uint2*>(&adjwT[(size_t)c * N_NODES + i0 + mrow]);
        #pragma unroll
        for (int kb = 0; kb < 2; kb++) {
            const int jb = c * 64 + kb * 32 + 8 * gl;
            half8_t sjv = *reinterpret_cast<const half8_t*>(&sjh[jb]);
            unsigned int bm8 = ((kb ? word.y : word.x) >> gl8) & 0xFFu;
            uint4 mk = *reinterpret_cast<const uint4*>(&ktab[bm8][0]);

            // packed: a1 = u + sj; a2 = 0.2*a1 + (-0.8 m); am = max(a1,a2)  (= lrelu(e)-m <= ~0)
            half8_t a1v = u8 + sjv;
            half8_t a2v = a1v * c028 + n88;
            half8_t amv = __builtin_elementwise_max(a1v, a2v);
            uint4 amu = __builtin_bit_cast(uint4, amv);
            uint4 pu;
            pu.x = exp2_pk_u(amu.x) & mk.x;            // AND with 0 => +0.0 (mask after exp)
            pu.y = exp2_pk_u(amu.y) & mk.y;
            pu.z = exp2_pk_u(amu.z) & mk.z;
            pu.w = exp2_pk_u(amu.w) & mk.w;
            half8_t af = __builtin_bit_cast(half8_t, pu);

            const _Float16* Bk = Bl + (size_t)(c * 2 + kb) * 2048;
            half8_t b0 = *reinterpret_cast<const half8_t*>(Bk);
            half8_t b1 = *reinterpret_cast<const half8_t*>(Bk + 512);
            half8_t b2 = *reinterpret_cast<const half8_t*>(Bk + 1024);
            half8_t b3 = *reinterpret_cast<const half8_t*>(Bk + 1536);

            acc0 = __builtin_amdgcn_mfma_f32_16x16x32_f16(af, b0, acc0, 0, 0, 0);
            acc1 = __builtin_amdgcn_mfma_f32_16x16x32_f16(af, b1, acc1, 0, 0, 0);
            acc2 = __builtin_amdgcn_mfma_f32_16x16x32_f16(af, b2, acc2, 0, 0, 0);
            acc3 = __builtin_amdgcn_mfma_f32_16x16x32_f16(af, b3, acc3, 0, 0, 0);
            accl = __builtin_amdgcn_mfma_f32_16x16x32_f16(af, vone, accl, 0, 0, 0);
        }
    }

    float* lp = lbuf + (size_t)jc * (H_HEADS * N_NODES);
    if (mrow == 0) {
        #pragma unroll
        for (int r = 0; r < 4; r++)
            lp[h * N_NODES + i0 + 4 * gl + r] = accl[r];
    }
    if (jc == 0) {
        #pragma unroll
        for (int r = 0; r < 4; r++) {
            int row   = i0 + 4 * gl + r;
            size_t ob = ((size_t)h * N_NODES + row) * 64 + mrow;
            out0[ob + 0]  = acc0[r];
            out0[ob + 16] = acc1[r];
            out0[ob + 32] = acc2[r];
            out0[ob + 48] = acc3[r];
        }
    } else {
        _Float16* op = partH + (size_t)(jc - 1) * ((size_t)H_HEADS * N_NODES * F_OUT);
        #pragma unroll
        for (int r = 0; r < 4; r++) {
            int row   = i0 + 4 * gl + r;
            size_t ob = ((size_t)h * N_NODES + row) * 64 + mrow;
            op[ob + 0]  = (_Float16)acc0[r];
            op[ob + 16] = (_Float16)acc1[r];
            op[ob + 32] = (_Float16)acc2[r];
            op[ob + 48] = (_Float16)acc3[r];
        }
    }
}

// ---------------- K4: out = (out + sum f16 partials) / sum l ----------------
__global__ __launch_bounds__(256) void k_norm(float* __restrict__ out,
                                              const _Float16* __restrict__ partH,
                                              const float* __restrict__ lbuf) {
    const int HN = H_HEADS * N_NODES;
    int idx = blockIdx.x * 256 + threadIdx.x;        // float4 index
    int row = idx >> 4;
    float inv = 1.0f / (lbuf[row] + lbuf[HN + row] + lbuf[2 * HN + row] + lbuf[3 * HN + row]);
    float4 a = reinterpret_cast<const float4*>(out)[idx];
    float s0 = a.x, s1 = a.y, s2 = a.z, s3 = a.w;
    #pragma unroll
    for (int p = 0; p < 3; p++) {
        half4_t hp = *reinterpret_cast<const half4_t*>(
            &partH[(size_t)p * ((size_t)H_HEADS * N_NODES * F_OUT) + (size_t)idx * 4]);
        s0 += (float)hp[0]; s1 += (float)hp[1]; s2 += (float)hp[2]; s3 += (float)hp[3];
    }
    float4 v = {s0 * inv, s1 * inv, s2 * inv, s3 * inv};
    reinterpret_cast<float4*>(out)[idx] = v;
}

// ---------------- launch ----------------
extern "C" void kernel_launch(void* const* d_in, const int* in_sizes, int n_in,
                              void* d_out, int out_size, void* d_ws, size_t ws_size,
                              hipStream_t stream) {
    const float* x     = (const float*)d_in[0];
    const int*   adj   = (const int*)d_in[1];
    const float* W     = (const float*)d_in[2];
    const float* a_src = (const float*)d_in[3];
    const float* a_tgt = (const float*)d_in[4];
    float* out = (float*)d_out;

    // workspace via accumulating allocator (R7 lesson: no hand-computed offsets)
    char* ws = (char*)d_ws;
    size_t off = 0;
    auto alloc = [&](size_t bytes) -> char* {
        char* p = ws + off;
        off += (bytes + 255) & ~(size_t)255;
        return p;
    };
    _Float16* WhFrag = (_Float16*)alloc((size_t)H_HEADS * N_NODES * F_OUT * 2);        // 4 MB
    _Float16* wfrag  = (_Float16*)alloc((size_t)H_HEADS * 16 * 4 * 64 * 8 * 2);        // 512 KB
    float* s_iL      = (float*)alloc((size_t)H_HEADS * N_NODES * 4);                   // 128 KB
    _Float16* s_jLh  = (_Float16*)alloc((size_t)H_HEADS * N_NODES * 2);                // 64 KB
    float* mxAll     = (float*)alloc((size_t)H_HEADS * 4);                             // 32 B
    float* lbuf      = (float*)alloc((size_t)JC * H_HEADS * N_NODES * 4);              // 512 KB
    _Float16* partH  = (_Float16*)alloc((size_t)(JC - 1) * H_HEADS * N_NODES * F_OUT * 2); // 12 MB
    unsigned long long* adjwT = (unsigned long long*)alloc((size_t)N_NODES * (N_NODES / 64) * 8); // 2 MB
    (void)ws_size;

    k_prep<<<2176, 256, 0, stream>>>(adj, W, adjwT, wfrag);
    k_wh_mfma<<<dim3(N_NODES / 64, H_HEADS), 512, 0, stream>>>(x, wfrag, a_src, a_tgt,
                                                               WhFrag, s_iL, s_jLh);
    k_hmax<<<H_HEADS, 256, 0, stream>>>(s_jLh, mxAll);
    k_attn_mfma<<<dim3(N_NODES / 64, H_HEADS, JC), 256, 0, stream>>>(WhFrag, s_iL, mxAll, s_jLh,
                                                                     adjwT, out, partH, lbuf);
    k_norm<<<(H_HEADS * N_NODES * F_OUT / 4) / 256, 256, 0, stream>>>(out, partH, lbuf);
}

// Round 10
// 82.579 us; speedup vs baseline: 4.7624x; 1.1716x over previous
//
#include <hip/hip_runtime.h>
#include <hip/hip_fp16.h>
#include <cstdint>

#define N_NODES 4096
#define F_IN    512
#define F_OUT   64
#define H_HEADS 8
#define JC      4          // j-sweep chunks for k_attn_mfma

constexpr float L2E = 1.44269504088896f;

typedef _Float16 half2_t __attribute__((ext_vector_type(2)));
typedef _Float16 half4_t __attribute__((ext_vector_type(4)));
typedef _Float16 half8_t __attribute__((ext_vector_type(8)));
typedef float    f32x4   __attribute__((ext_vector_type(4)));

__device__ inline unsigned int exp2_pk_u(unsigned int au) {
    __half2 h = __builtin_bit_cast(__half2, au);
    h = h2exp2(h);
    return __builtin_bit_cast(unsigned int, h);
}

// ---------------- K0: merged W-pack (blocks 0..127) + adj bitmask -> adjwT (blocks 128..2175) ----------------
// wfrag: [h][kt(16)][ntile(4)][lane(64)][t(8)], value = W[h][kt*32+8*(lane>>4)+t][ntile*16+(lane&15)]
__global__ __launch_bounds__(256) void k_prep(const int* __restrict__ adj,
                                              const float* __restrict__ W,
                                              unsigned long long* __restrict__ adjwT,
                                              _Float16* __restrict__ wfrag) {
    if (blockIdx.x < 128) {
        int gid = blockIdx.x * 256 + threadIdx.x;         // 0 .. 32767
        int h     = gid >> 12;
        int kt    = (gid >> 8) & 15;
        int ntile = (gid >> 6) & 3;
        int lane  = gid & 63;
        int c0 = lane & 15, g = lane >> 4;
        const float* src = W + ((size_t)h * F_IN + kt * 32 + 8 * g) * F_OUT + ntile * 16 + c0;
        half8_t hv;
        #pragma unroll
        for (int t = 0; t < 8; t++) hv[t] = (_Float16)src[(size_t)t * F_OUT];
        *reinterpret_cast<half8_t*>(&wfrag[(size_t)gid * 8]) = hv;
        return;
    }
    int bid  = blockIdx.x - 128;                          // 0..2047
    int lane = threadIdx.x & 63;
    int wid  = (int)((bid * 256 + threadIdx.x) >> 6);
    int nwaves = (2048 * 256) >> 6;
    const int nchunks = N_NODES * (N_NODES / 64);
    for (int cf = wid; cf < nchunks; cf += nwaves) {
        int v = adj[(size_t)cf * 64 + lane];
        unsigned long long mask = __ballot(v > 0);
        if (lane == 0) {
            int i = cf >> 6, c = cf & 63;
            adjwT[(size_t)c * N_NODES + i] = mask;        // [c][i] for k_attn
        }
    }
}

// ---------------- K1: Wh = x @ W[h] via MFMA 16x16x32, K-split x2 + LDS reduce ----------------
// grid (64, 8), block 512 (8 waves): wave w -> mtw = w&3, kh = w>>2. mt = rt*4 + mtw.
__global__ __launch_bounds__(512) void k_wh_mfma(const float* __restrict__ x,
                                                 const _Float16* __restrict__ wfrag,
                                                 const float* __restrict__ a_src,
                                                 const float* __restrict__ a_tgt,
                                                 _Float16* __restrict__ WhFrag,
                                                 float* __restrict__ s_iL,
                                                 _Float16* __restrict__ s_jLh) {
    __shared__ f32x4 red[4][4][64];                       // 16 KB
    const int h    = blockIdx.y;
    const int rt   = blockIdx.x;
    const int t    = threadIdx.x;
    const int lane = t & 63;
    const int w    = t >> 6;
    const int mtw  = w & 3;
    const int kh   = w >> 2;
    const int mt   = rt * 4 + mtw;          // 16-row m-tile index (0..255)
    const int c0   = lane & 15;
    const int gl   = lane >> 4;

    f32x4 acc0 = {0.f, 0.f, 0.f, 0.f};
    f32x4 acc1 = {0.f, 0.f, 0.f, 0.f};
    f32x4 acc2 = {0.f, 0.f, 0.f, 0.f};
    f32x4 acc3 = {0.f, 0.f, 0.f, 0.f};

    const float* __restrict__ xr = x + (size_t)(mt * 16 + c0) * F_IN + 8 * gl + kh * 256;
    const _Float16* __restrict__ Bf = wfrag + (size_t)h * (16 * 4 * 512)
                                    + (size_t)kh * 8 * 2048 + (size_t)lane * 8;

    #pragma unroll
    for (int kt = 0; kt < 8; kt++) {
        float4 v0 = *reinterpret_cast<const float4*>(xr + kt * 32);
        float4 v1 = *reinterpret_cast<const float4*>(xr + kt * 32 + 4);
        half8_t a;
        a[0] = (_Float16)v0.x; a[1] = (_Float16)v0.y; a[2] = (_Float16)v0.z; a[3] = (_Float16)v0.w;
        a[4] = (_Float16)v1.x; a[5] = (_Float16)v1.y; a[6] = (_Float16)v1.z; a[7] = (_Float16)v1.w;
        const _Float16* Bk = Bf + (size_t)kt * 2048;
        half8_t b0 = *reinterpret_cast<const half8_t*>(Bk);
        half8_t b1 = *reinterpret_cast<const half8_t*>(Bk + 512);
        half8_t b2 = *reinterpret_cast<const half8_t*>(Bk + 1024);
        half8_t b3 = *reinterpret_cast<const half8_t*>(Bk + 1536);
        acc0 = __builtin_amdgcn_mfma_f32_16x16x32_f16(a, b0, acc0, 0, 0, 0);
        acc1 = __builtin_amdgcn_mfma_f32_16x16x32_f16(a, b1, acc1, 0, 0, 0);
        acc2 = __builtin_amdgcn_mfma_f32_16x16x32_f16(a, b2, acc2, 0, 0, 0);
        acc3 = __builtin_amdgcn_mfma_f32_16x16x32_f16(a, b3, acc3, 0, 0, 0);
    }

    if (kh == 1) {
        red[mtw][0][lane] = acc0;
        red[mtw][1][lane] = acc1;
        red[mtw][2][lane] = acc2;
        red[mtw][3][lane] = acc3;
    }
    __syncthreads();
    if (kh == 1) return;

    acc0 += red[mtw][0][lane];
    acc1 += red[mtw][1][lane];
    acc2 += red[mtw][2][lane];
    acc3 += red[mtw][3][lane];

    const float as0 = a_src[h * 64 + c0],      at0 = a_tgt[h * 64 + c0];
    const float as1 = a_src[h * 64 + 16 + c0], at1 = a_tgt[h * 64 + 16 + c0];
    const float as2 = a_src[h * 64 + 32 + c0], at2 = a_tgt[h * 64 + 32 + c0];
    const float as3 = a_src[h * 64 + 48 + c0], at3 = a_tgt[h * 64 + 48 + c0];

    #pragma unroll
    for (int reg = 0; reg < 4; reg++) {
        float vi = acc0[reg] * as0 + acc1[reg] * as1 + acc2[reg] * as2 + acc3[reg] * as3;
        float vj = acc0[reg] * at0 + acc1[reg] * at1 + acc2[reg] * at2 + acc3[reg] * at3;
        #pragma unroll
        for (int mm = 8; mm >= 1; mm >>= 1) {
            vi += __shfl_xor(vi, mm, 64);
            vj += __shfl_xor(vj, mm, 64);
        }
        if (c0 == 0) {
            int row = mt * 16 + 4 * gl + reg;
            s_iL[h * N_NODES + row]  = vi * L2E;
            s_jLh[h * N_NODES + row] = (_Float16)(vj * L2E);
        }
    }

    const int cc    = mt >> 2;
    const int kb    = (mt >> 1) & 1;
    const int lanep = c0 + 16 * ((mt & 1) * 2 + (gl >> 1));
    const int tb    = 4 * (gl & 1);
    _Float16* dst = WhFrag + (size_t)h * (N_NODES * 64)
                  + (size_t)(cc * 2 + kb) * 2048 + (size_t)lanep * 8 + tb;
    f32x4 accs[4] = {acc0, acc1, acc2, acc3};
    #pragma unroll
    for (int ot = 0; ot < 4; ot++) {
        half4_t hv;
        #pragma unroll
        for (int reg = 0; reg < 4; reg++) hv[reg] = (_Float16)accs[ot][reg];
        *reinterpret_cast<half4_t*>(dst + ot * 512) = hv;
    }
}

// ---------------- K2: per-head global max of s_jLh (softmax shift; adjacency-free) ----------------
__global__ __launch_bounds__(256) void k_hmax(const _Float16* __restrict__ s_jLh,
                                              float* __restrict__ mxAll) {
    __shared__ float red[4];
    const int h = blockIdx.x;
    const int t = threadIdx.x;
    const _Float16* p = s_jLh + h * N_NODES;
    float m = -INFINITY;
    for (int k = t; k < N_NODES; k += 256) m = fmaxf(m, (float)p[k]);
    #pragma unroll
    for (int mm = 32; mm >= 1; mm >>= 1) m = fmaxf(m, __shfl_xor(m, mm, 64));
    if ((t & 63) == 0) red[t >> 6] = m;
    __syncthreads();
    if (t == 0) mxAll[h] = fmaxf(fmaxf(red[0], red[1]), fmaxf(red[2], red[3]));
}

// ---------------- K3: LDS-staged B (4x L2 reuse) + packed-f16 P + PV via mfma 16x16x32 ----------------
// grid (64, 8, JC), block 256 (4 waves). Per c-iter the block's 8KB B-chunk is staged
// to LDS once (double-buffered, 1 barrier/c); all 4 waves ds_read it.
__global__ __launch_bounds__(256) void k_attn_mfma(const _Float16* __restrict__ WhFrag,
                                                   const float* __restrict__ s_iL,
                                                   const float* __restrict__ mxAll,
                                                   const _Float16* __restrict__ s_jLh,
                                                   const unsigned long long* __restrict__ adjwT,
                                                   float* __restrict__ out0,
                                                   _Float16* __restrict__ partH,
                                                   float* __restrict__ lbuf) {
    __shared__ unsigned int ktab[256][4];   // bm8 -> 4 packed halfword KEEP masks
    __shared__ _Float16 Bs[2][4096];        // 2 x 8KB: one c-chunk [kb(2)][nt(4)][lane(64)][8]
    {
        unsigned int bm = threadIdx.x;
        #pragma unroll
        for (int q = 0; q < 4; q++) {
            unsigned int lo = ((bm >> (2 * q)) & 1u) ? 0xFFFFu : 0u;
            unsigned int hi = ((bm >> (2 * q + 1)) & 1u) ? 0xFFFF0000u : 0u;
            ktab[bm][q] = lo | hi;
        }
    }

    const int tid  = threadIdx.x;
    const int h    = blockIdx.y;
    const int jc   = blockIdx.z;
    const int lane = tid & 63;
    const int w    = tid >> 6;
    const int i0   = blockIdx.x * 64 + w * 16;
    const int mrow = lane & 15;
    const int gl   = lane >> 4;
    const int gl8  = gl << 3;

    const float siL = s_iL[h * N_NODES + i0 + mrow];
    const float tmx = siL + mxAll[h];
    const float m   = fmaxf(tmx, 0.2f * tmx);          // row shift (>= true masked max)
    const _Float16 uh  = (_Float16)(siL - m);
    const _Float16 n8h = (_Float16)(-0.8f * m);
    half8_t u8, n88, c028;
    #pragma unroll
    for (int q = 0; q < 8; q++) { u8[q] = uh; n88[q] = n8h; c028[q] = (_Float16)0.2f; }

    const _Float16* __restrict__ sjh = s_jLh + h * N_NODES;
    const _Float16* __restrict__ Bh  = WhFrag + (size_t)h * (N_NODES * 64);

    half8_t vone;
    #pragma unroll
    for (int q = 0; q < 8; q++) vone[q] = (_Float16)1.0f;

    f32x4 acc0 = {0.f, 0.f, 0.f, 0.f};
    f32x4 acc1 = {0.f, 0.f, 0.f, 0.f};
    f32x4 acc2 = {0.f, 0.f, 0.f, 0.f};
    f32x4 acc3 = {0.f, 0.f, 0.f, 0.f};
    f32x4 accl = {0.f, 0.f, 0.f, 0.f};

    const int NC   = (N_NODES / 64) / JC;   // 16
    const int cbeg = jc * NC;
    const int cend = cbeg + NC;

    // prologue: stage c = cbeg into Bs[0] (stride-16B writes: conflict-free)
    {
        const _Float16* src = Bh + (size_t)cbeg * 4096 + tid * 8;
        *reinterpret_cast<half8_t*>(&Bs[0][tid * 8])        = *reinterpret_cast<const half8_t*>(src);
        *reinterpret_cast<half8_t*>(&Bs[0][2048 + tid * 8]) = *reinterpret_cast<const half8_t*>(src + 2048);
    }
    __syncthreads();

    int cur = 0;
    for (int c = cbeg; c < cend; c++) {
        // issue next chunk's global loads early (hide under compute)
        half8_t n0, n1;
        const bool hasNext = (c + 1 < cend);
        if (hasNext) {
            const _Float16* src = Bh + (size_t)(c + 1) * 4096 + tid * 8;
            n0 = *reinterpret_cast<const half8_t*>(src);
            n1 = *reinterpret_cast<const half8_t*>(src + 2048);
        }

        uint2 word = *reinterpret_cast<const uint2*>(&adjwT[(size_t)c * N_NODES + i0 + mrow]);
        #pragma unroll
        for (int kb = 0; kb < 2; kb++) {
            const int jb = c * 64 + kb * 32 + 8 * gl;
            half8_t sjv = *reinterpret_cast<const half8_t*>(&sjh[jb]);
            unsigned int bm8 = ((kb ? word.y : word.x) >> gl8) & 0xFFu;
            uint4 mk = *reinterpret_cast<const uint4*>(&ktab[bm8][0]);

            half8_t a1v = u8 + sjv;
            half8_t a2v = a1v * c028 + n88;
            half8_t amv = __builtin_elementwise_max(a1v, a2v);
            uint4 amu = __builtin_bit_cast(uint4, amv);
            uint4 pu;
            pu.x = exp2_pk_u(amu.x) & mk.x;
            pu.y = exp2_pk_u(amu.y) & mk.y;
            pu.z = exp2_pk_u(amu.z) & mk.z;
            pu.w = exp2_pk_u(amu.w) & mk.w;
            half8_t af = __builtin_bit_cast(half8_t, pu);

            const _Float16* Bk = &Bs[cur][kb * 2048 + lane * 8];
            half8_t b0 = *reinterpret_cast<const half8_t*>(Bk);
            half8_t b1 = *reinterpret_cast<const half8_t*>(Bk + 512);
            half8_t b2 = *reinterpret_cast<const half8_t*>(Bk + 1024);
            half8_t b3 = *reinterpret_cast<const half8_t*>(Bk + 1536);

            acc0 = __builtin_amdgcn_mfma_f32_16x16x32_f16(af, b0, acc0, 0, 0, 0);
            acc1 = __builtin_amdgcn_mfma_f32_16x16x32_f16(af, b1, acc1, 0, 0, 0);
            acc2 = __builtin_amdgcn_mfma_f32_16x16x32_f16(af, b2, acc2, 0, 0, 0);
            acc3 = __builtin_amdgcn_mfma_f32_16x16x32_f16(af, b3, acc3, 0, 0, 0);
            accl = __builtin_amdgcn_mfma_f32_16x16x32_f16(af, vone, accl, 0, 0, 0);
        }

        if (hasNext) {
            *reinterpret_cast<half8_t*>(&Bs[cur ^ 1][tid * 8])        = n0;
            *reinterpret_cast<half8_t*>(&Bs[cur ^ 1][2048 + tid * 8]) = n1;
        }
        __syncthreads();
        cur ^= 1;
    }

    float* lp = lbuf + (size_t)jc * (H_HEADS * N_NODES);
    if (mrow == 0) {
        #pragma unroll
        for (int r = 0; r < 4; r++)
            lp[h * N_NODES + i0 + 4 * gl + r] = accl[r];
    }
    if (jc == 0) {
        #pragma unroll
        for (int r = 0; r < 4; r++) {
            int row   = i0 + 4 * gl + r;
            size_t ob = ((size_t)h * N_NODES + row) * 64 + mrow;
            out0[ob + 0]  = acc0[r];
            out0[ob + 16] = acc1[r];
            out0[ob + 32] = acc2[r];
            out0[ob + 48] = acc3[r];
        }
    } else {
        _Float16* op = partH + (size_t)(jc - 1) * ((size_t)H_HEADS * N_NODES * F_OUT);
        #pragma unroll
        for (int r = 0; r < 4; r++) {
            int row   = i0 + 4 * gl + r;
            size_t ob = ((size_t)h * N_NODES + row) * 64 + mrow;
            op[ob + 0]  = (_Float16)acc0[r];
            op[ob + 16] = (_Float16)acc1[r];
            op[ob + 32] = (_Float16)acc2[r];
            op[ob + 48] = (_Float16)acc3[r];
        }
    }
}

// ---------------- K4: out = (out + sum f16 partials) / sum l ----------------
__global__ __launch_bounds__(256) void k_norm(float* __restrict__ out,
                                              const _Float16* __restrict__ partH,
                                              const float* __restrict__ lbuf) {
    const int HN = H_HEADS * N_NODES;
    int idx = blockIdx.x * 256 + threadIdx.x;        // float4 index
    int row = idx >> 4;
    float inv = 1.0f / (lbuf[row] + lbuf[HN + row] + lbuf[2 * HN + row] + lbuf[3 * HN + row]);
    float4 a = reinterpret_cast<const float4*>(out)[idx];
    float s0 = a.x, s1 = a.y, s2 = a.z, s3 = a.w;
    #pragma unroll
    for (int p = 0; p < 3; p++) {
        half4_t hp = *reinterpret_cast<const half4_t*>(
            &partH[(size_t)p * ((size_t)H_HEADS * N_NODES * F_OUT) + (size_t)idx * 4]);
        s0 += (float)hp[0]; s1 += (float)hp[1]; s2 += (float)hp[2]; s3 += (float)hp[3];
    }
    float4 v = {s0 * inv, s1 * inv, s2 * inv, s3 * inv};
    reinterpret_cast<float4*>(out)[idx] = v;
}

// ---------------- launch ----------------
extern "C" void kernel_launch(void* const* d_in, const int* in_sizes, int n_in,
                              void* d_out, int out_size, void* d_ws, size_t ws_size,
                              hipStream_t stream) {
    const float* x     = (const float*)d_in[0];
    const int*   adj   = (const int*)d_in[1];
    const float* W     = (const float*)d_in[2];
    const float* a_src = (const float*)d_in[3];
    const float* a_tgt = (const float*)d_in[4];
    float* out = (float*)d_out;

    // workspace via accumulating allocator (R7 lesson: no hand-computed offsets)
    char* ws = (char*)d_ws;
    size_t off = 0;
    auto alloc = [&](size_t bytes) -> char* {
        char* p = ws + off;
        off += (bytes + 255) & ~(size_t)255;
        return p;
    };
    _Float16* WhFrag = (_Float16*)alloc((size_t)H_HEADS * N_NODES * F_OUT * 2);        // 4 MB
    _Float16* wfrag  = (_Float16*)alloc((size_t)H_HEADS * 16 * 4 * 64 * 8 * 2);        // 512 KB
    float* s_iL      = (float*)alloc((size_t)H_HEADS * N_NODES * 4);                   // 128 KB
    _Float16* s_jLh  = (_Float16*)alloc((size_t)H_HEADS * N_NODES * 2);                // 64 KB
    float* mxAll     = (float*)alloc((size_t)H_HEADS * 4);                             // 32 B
    float* lbuf      = (float*)alloc((size_t)JC * H_HEADS * N_NODES * 4);              // 512 KB
    _Float16* partH  = (_Float16*)alloc((size_t)(JC - 1) * H_HEADS * N_NODES * F_OUT * 2); // 12 MB
    unsigned long long* adjwT = (unsigned long long*)alloc((size_t)N_NODES * (N_NODES / 64) * 8); // 2 MB
    (void)ws_size;

    k_prep<<<2176, 256, 0, stream>>>(adj, W, adjwT, wfrag);
    k_wh_mfma<<<dim3(N_NODES / 64, H_HEADS), 512, 0, stream>>>(x, wfrag, a_src, a_tgt,
                                                               WhFrag, s_iL, s_jLh);
    k_hmax<<<H_HEADS, 256, 0, stream>>>(s_jLh, mxAll);
    k_attn_mfma<<<dim3(N_NODES / 64, H_HEADS, JC), 256, 0, stream>>>(WhFrag, s_iL, mxAll, s_jLh,
                                                                     adjwT, out, partH, lbuf);
    k_norm<<<(H_HEADS * N_NODES * F_OUT / 4) / 256, 256, 0, stream>>>(out, partH, lbuf);
}

// Round 11
// 79.230 us; speedup vs baseline: 4.9637x; 1.0423x over previous
//
#include <hip/hip_runtime.h>
#include <hip/hip_fp16.h>
#include <cstdint>

#define N_NODES 4096
#define F_IN    512
#define F_OUT   64
#define H_HEADS 8
#define JC      4          // j-sweep chunks for k_attn_mfma

constexpr float L2E = 1.44269504088896f;

typedef _Float16 half2_t __attribute__((ext_vector_type(2)));
typedef _Float16 half4_t __attribute__((ext_vector_type(4)));
typedef _Float16 half8_t __attribute__((ext_vector_type(8)));
typedef float    f32x4   __attribute__((ext_vector_type(4)));

__device__ inline unsigned int exp2_pk_u(unsigned int au) {
    __half2 h = __builtin_bit_cast(__half2, au);
    h = h2exp2(h);
    return __builtin_bit_cast(unsigned int, h);
}

// ---------------- K0: merged W-pack (blocks 0..127) + adj bitmask -> adjwT (blocks 128..2175) ----------------
__global__ __launch_bounds__(256) void k_prep(const int* __restrict__ adj,
                                              const float* __restrict__ W,
                                              unsigned long long* __restrict__ adjwT,
                                              _Float16* __restrict__ wfrag) {
    if (blockIdx.x < 128) {
        int gid = blockIdx.x * 256 + threadIdx.x;         // 0 .. 32767
        int h     = gid >> 12;
        int kt    = (gid >> 8) & 15;
        int ntile = (gid >> 6) & 3;
        int lane  = gid & 63;
        int c0 = lane & 15, g = lane >> 4;
        const float* src = W + ((size_t)h * F_IN + kt * 32 + 8 * g) * F_OUT + ntile * 16 + c0;
        half8_t hv;
        #pragma unroll
        for (int t = 0; t < 8; t++) hv[t] = (_Float16)src[(size_t)t * F_OUT];
        *reinterpret_cast<half8_t*>(&wfrag[(size_t)gid * 8]) = hv;
        return;
    }
    int bid  = blockIdx.x - 128;                          // 0..2047
    int lane = threadIdx.x & 63;
    int wid  = (int)((bid * 256 + threadIdx.x) >> 6);
    int nwaves = (2048 * 256) >> 6;
    const int nchunks = N_NODES * (N_NODES / 64);
    for (int cf = wid; cf < nchunks; cf += nwaves) {
        int v = adj[(size_t)cf * 64 + lane];
        unsigned long long mask = __ballot(v > 0);
        if (lane == 0) {
            int i = cf >> 6, c = cf & 63;
            adjwT[(size_t)c * N_NODES + i] = mask;        // [c][i] for k_attn
        }
    }
}

// ---------------- K1: Wh = x @ W[h] via MFMA 16x16x32, K-split x2 + LDS reduce ----------------
__global__ __launch_bounds__(512) void k_wh_mfma(const float* __restrict__ x,
                                                 const _Float16* __restrict__ wfrag,
                                                 const float* __restrict__ a_src,
                                                 const float* __restrict__ a_tgt,
                                                 _Float16* __restrict__ WhFrag,
                                                 float* __restrict__ s_iL,
                                                 _Float16* __restrict__ s_jLh) {
    __shared__ f32x4 red[4][4][64];                       // 16 KB
    const int h    = blockIdx.y;
    const int rt   = blockIdx.x;
    const int t    = threadIdx.x;
    const int lane = t & 63;
    const int w    = t >> 6;
    const int mtw  = w & 3;
    const int kh   = w >> 2;
    const int mt   = rt * 4 + mtw;          // 16-row m-tile index (0..255)
    const int c0   = lane & 15;
    const int gl   = lane >> 4;

    f32x4 acc0 = {0.f, 0.f, 0.f, 0.f};
    f32x4 acc1 = {0.f, 0.f, 0.f, 0.f};
    f32x4 acc2 = {0.f, 0.f, 0.f, 0.f};
    f32x4 acc3 = {0.f, 0.f, 0.f, 0.f};

    const float* __restrict__ xr = x + (size_t)(mt * 16 + c0) * F_IN + 8 * gl + kh * 256;
    const _Float16* __restrict__ Bf = wfrag + (size_t)h * (16 * 4 * 512)
                                    + (size_t)kh * 8 * 2048 + (size_t)lane * 8;

    #pragma unroll
    for (int kt = 0; kt < 8; kt++) {
        float4 v0 = *reinterpret_cast<const float4*>(xr + kt * 32);
        float4 v1 = *reinterpret_cast<const float4*>(xr + kt * 32 + 4);
        half8_t a;
        a[0] = (_Float16)v0.x; a[1] = (_Float16)v0.y; a[2] = (_Float16)v0.z; a[3] = (_Float16)v0.w;
        a[4] = (_Float16)v1.x; a[5] = (_Float16)v1.y; a[6] = (_Float16)v1.z; a[7] = (_Float16)v1.w;
        const _Float16* Bk = Bf + (size_t)kt * 2048;
        half8_t b0 = *reinterpret_cast<const half8_t*>(Bk);
        half8_t b1 = *reinterpret_cast<const half8_t*>(Bk + 512);
        half8_t b2 = *reinterpret_cast<const half8_t*>(Bk + 1024);
        half8_t b3 = *reinterpret_cast<const half8_t*>(Bk + 1536);
        acc0 = __builtin_amdgcn_mfma_f32_16x16x32_f16(a, b0, acc0, 0, 0, 0);
        acc1 = __builtin_amdgcn_mfma_f32_16x16x32_f16(a, b1, acc1, 0, 0, 0);
        acc2 = __builtin_amdgcn_mfma_f32_16x16x32_f16(a, b2, acc2, 0, 0, 0);
        acc3 = __builtin_amdgcn_mfma_f32_16x16x32_f16(a, b3, acc3, 0, 0, 0);
    }

    if (kh == 1) {
        red[mtw][0][lane] = acc0;
        red[mtw][1][lane] = acc1;
        red[mtw][2][lane] = acc2;
        red[mtw][3][lane] = acc3;
    }
    __syncthreads();
    if (kh == 1) return;

    acc0 += red[mtw][0][lane];
    acc1 += red[mtw][1][lane];
    acc2 += red[mtw][2][lane];
    acc3 += red[mtw][3][lane];

    const float as0 = a_src[h * 64 + c0],      at0 = a_tgt[h * 64 + c0];
    const float as1 = a_src[h * 64 + 16 + c0], at1 = a_tgt[h * 64 + 16 + c0];
    const float as2 = a_src[h * 64 + 32 + c0], at2 = a_tgt[h * 64 + 32 + c0];
    const float as3 = a_src[h * 64 + 48 + c0], at3 = a_tgt[h * 64 + 48 + c0];

    #pragma unroll
    for (int reg = 0; reg < 4; reg++) {
        float vi = acc0[reg] * as0 + acc1[reg] * as1 + acc2[reg] * as2 + acc3[reg] * as3;
        float vj = acc0[reg] * at0 + acc1[reg] * at1 + acc2[reg] * at2 + acc3[reg] * at3;
        #pragma unroll
        for (int mm = 8; mm >= 1; mm >>= 1) {
            vi += __shfl_xor(vi, mm, 64);
            vj += __shfl_xor(vj, mm, 64);
        }
        if (c0 == 0) {
            int row = mt * 16 + 4 * gl + reg;
            s_iL[h * N_NODES + row]  = vi * L2E;
            s_jLh[h * N_NODES + row] = (_Float16)(vj * L2E);
        }
    }

    const int cc    = mt >> 2;
    const int kb    = (mt >> 1) & 1;
    const int lanep = c0 + 16 * ((mt & 1) * 2 + (gl >> 1));
    const int tb    = 4 * (gl & 1);
    _Float16* dst = WhFrag + (size_t)h * (N_NODES * 64)
                  + (size_t)(cc * 2 + kb) * 2048 + (size_t)lanep * 8 + tb;
    f32x4 accs[4] = {acc0, acc1, acc2, acc3};
    #pragma unroll
    for (int ot = 0; ot < 4; ot++) {
        half4_t hv;
        #pragma unroll
        for (int reg = 0; reg < 4; reg++) hv[reg] = (_Float16)accs[ot][reg];
        *reinterpret_cast<half4_t*>(dst + ot * 512) = hv;
    }
}

// ---------------- K2: per-head global max of s_jLh (softmax shift; adjacency-free) ----------------
__global__ __launch_bounds__(256) void k_hmax(const _Float16* __restrict__ s_jLh,
                                              float* __restrict__ mxAll) {
    __shared__ float red[4];
    const int h = blockIdx.x;
    const int t = threadIdx.x;
    const _Float16* p = s_jLh + h * N_NODES;
    float m = -INFINITY;
    for (int k = t; k < N_NODES; k += 256) m = fmaxf(m, (float)p[k]);
    #pragma unroll
    for (int mm = 32; mm >= 1; mm >>= 1) m = fmaxf(m, __shfl_xor(m, mm, 64));
    if ((t & 63) == 0) red[t >> 6] = m;
    __syncthreads();
    if (t == 0) mxAll[h] = fmaxf(fmaxf(red[0], red[1]), fmaxf(red[2], red[3]));
}

// ---------------- K3: 32 rows/wave (2 A-tiles per B-read) + LDS-staged B + packed-f16 P ----------------
// grid (32, 8, JC), block 256 (4 waves). Wave: rows i0..i0+31 (two 16-row tiles), 64 o.
__global__ __launch_bounds__(256, 4) void k_attn_mfma(const _Float16* __restrict__ WhFrag,
                                                      const float* __restrict__ s_iL,
                                                      const float* __restrict__ mxAll,
                                                      const _Float16* __restrict__ s_jLh,
                                                      const unsigned long long* __restrict__ adjwT,
                                                      float* __restrict__ out0,
                                                      _Float16* __restrict__ partH,
                                                      float* __restrict__ lbuf) {
    __shared__ unsigned int ktab[256][4];   // bm8 -> 4 packed halfword KEEP masks
    __shared__ _Float16 Bs[2][4096];        // 2 x 8KB: one c-chunk [kb(2)][nt(4)][lane(64)][8]
    {
        unsigned int bm = threadIdx.x;
        #pragma unroll
        for (int q = 0; q < 4; q++) {
            unsigned int lo = ((bm >> (2 * q)) & 1u) ? 0xFFFFu : 0u;
            unsigned int hi = ((bm >> (2 * q + 1)) & 1u) ? 0xFFFF0000u : 0u;
            ktab[bm][q] = lo | hi;
        }
    }

    const int tid  = threadIdx.x;
    const int h    = blockIdx.y;
    const int jc   = blockIdx.z;
    const int lane = tid & 63;
    const int w    = tid >> 6;
    const int i0   = blockIdx.x * 128 + w * 32;     // wave's 32 rows
    const int mrow = lane & 15;
    const int gl   = lane >> 4;
    const int gl8  = gl << 3;

    // per-tile row constants (tile A: i0+mrow, tile B: i0+16+mrow)
    const float siL0 = s_iL[h * N_NODES + i0 + mrow];
    const float siL1 = s_iL[h * N_NODES + i0 + 16 + mrow];
    const float mxh  = mxAll[h];
    const float tm0 = siL0 + mxh, tm1 = siL1 + mxh;
    const float m0 = fmaxf(tm0, 0.2f * tm0);
    const float m1 = fmaxf(tm1, 0.2f * tm1);
    const half2_t u2_0 = {(_Float16)(siL0 - m0), (_Float16)(siL0 - m0)};
    const half2_t u2_1 = {(_Float16)(siL1 - m1), (_Float16)(siL1 - m1)};
    const half2_t n82_0 = {(_Float16)(-0.8f * m0), (_Float16)(-0.8f * m0)};
    const half2_t n82_1 = {(_Float16)(-0.8f * m1), (_Float16)(-0.8f * m1)};
    const half2_t c02 = {(_Float16)0.2f, (_Float16)0.2f};

    const _Float16* __restrict__ sjh = s_jLh + h * N_NODES;
    const _Float16* __restrict__ Bh  = WhFrag + (size_t)h * (N_NODES * 64);

    half8_t vone;
    #pragma unroll
    for (int q = 0; q < 8; q++) vone[q] = (_Float16)1.0f;

    f32x4 accA0 = {0,0,0,0}, accA1 = {0,0,0,0}, accA2 = {0,0,0,0}, accA3 = {0,0,0,0};
    f32x4 accB0 = {0,0,0,0}, accB1 = {0,0,0,0}, accB2 = {0,0,0,0}, accB3 = {0,0,0,0};
    f32x4 acclA = {0,0,0,0}, acclB = {0,0,0,0};

    const int NC   = (N_NODES / 64) / JC;   // 16
    const int cbeg = jc * NC;
    const int cend = cbeg + NC;

    {   // prologue stage
        const _Float16* src = Bh + (size_t)cbeg * 4096 + tid * 8;
        *reinterpret_cast<half8_t*>(&Bs[0][tid * 8])        = *reinterpret_cast<const half8_t*>(src);
        *reinterpret_cast<half8_t*>(&Bs[0][2048 + tid * 8]) = *reinterpret_cast<const half8_t*>(src + 2048);
    }
    __syncthreads();

    int cur = 0;
    for (int c = cbeg; c < cend; c++) {
        half8_t n0, n1;
        const bool hasNext = (c + 1 < cend);
        if (hasNext) {
            const _Float16* src = Bh + (size_t)(c + 1) * 4096 + tid * 8;
            n0 = *reinterpret_cast<const half8_t*>(src);
            n1 = *reinterpret_cast<const half8_t*>(src + 2048);
        }

        uint2 word0 = *reinterpret_cast<const uint2*>(&adjwT[(size_t)c * N_NODES + i0 + mrow]);
        uint2 word1 = *reinterpret_cast<const uint2*>(&adjwT[(size_t)c * N_NODES + i0 + 16 + mrow]);

        #pragma unroll
        for (int kb = 0; kb < 2; kb++) {
            const int jb = c * 64 + kb * 32 + 8 * gl;
            half8_t sjv = *reinterpret_cast<const half8_t*>(&sjh[jb]);
            unsigned int bm0 = ((kb ? word0.y : word0.x) >> gl8) & 0xFFu;
            unsigned int bm1 = ((kb ? word1.y : word1.x) >> gl8) & 0xFFu;
            uint4 mk0 = *reinterpret_cast<const uint4*>(&ktab[bm0][0]);
            uint4 mk1 = *reinterpret_cast<const uint4*>(&ktab[bm1][0]);

            uint4 sju = __builtin_bit_cast(uint4, sjv);
            uint4 p0u, p1u;
            #pragma unroll
            for (int q = 0; q < 4; q++) {
                unsigned int sw = (q == 0) ? sju.x : (q == 1) ? sju.y : (q == 2) ? sju.z : sju.w;
                half2_t sj2 = __builtin_bit_cast(half2_t, sw);
                // tile A
                half2_t a1 = u2_0 + sj2;
                half2_t am = __builtin_elementwise_max(a1, a1 * c02 + n82_0);
                unsigned int pa = exp2_pk_u(__builtin_bit_cast(unsigned int, am));
                // tile B
                half2_t b1 = u2_1 + sj2;
                half2_t bm = __builtin_elementwise_max(b1, b1 * c02 + n82_1);
                unsigned int pb = exp2_pk_u(__builtin_bit_cast(unsigned int, bm));
                unsigned int ka = (q == 0) ? mk0.x : (q == 1) ? mk0.y : (q == 2) ? mk0.z : mk0.w;
                unsigned int kbm = (q == 0) ? mk1.x : (q == 1) ? mk1.y : (q == 2) ? mk1.z : mk1.w;
                pa &= ka; pb &= kbm;
                if (q == 0) { p0u.x = pa; p1u.x = pb; }
                else if (q == 1) { p0u.y = pa; p1u.y = pb; }
                else if (q == 2) { p0u.z = pa; p1u.z = pb; }
                else { p0u.w = pa; p1u.w = pb; }
            }
            half8_t af0 = __builtin_bit_cast(half8_t, p0u);
            half8_t af1 = __builtin_bit_cast(half8_t, p1u);

            const _Float16* Bk = &Bs[cur][kb * 2048 + lane * 8];
            half8_t b0 = *reinterpret_cast<const half8_t*>(Bk);
            half8_t b1v = *reinterpret_cast<const half8_t*>(Bk + 512);
            half8_t b2 = *reinterpret_cast<const half8_t*>(Bk + 1024);
            half8_t b3 = *reinterpret_cast<const half8_t*>(Bk + 1536);

            accA0 = __builtin_amdgcn_mfma_f32_16x16x32_f16(af0, b0,  accA0, 0, 0, 0);
            accB0 = __builtin_amdgcn_mfma_f32_16x16x32_f16(af1, b0,  accB0, 0, 0, 0);
            accA1 = __builtin_amdgcn_mfma_f32_16x16x32_f16(af0, b1v, accA1, 0, 0, 0);
            accB1 = __builtin_amdgcn_mfma_f32_16x16x32_f16(af1, b1v, accB1, 0, 0, 0);
            accA2 = __builtin_amdgcn_mfma_f32_16x16x32_f16(af0, b2,  accA2, 0, 0, 0);
            accB2 = __builtin_amdgcn_mfma_f32_16x16x32_f16(af1, b2,  accB2, 0, 0, 0);
            accA3 = __builtin_amdgcn_mfma_f32_16x16x32_f16(af0, b3,  accA3, 0, 0, 0);
            accB3 = __builtin_amdgcn_mfma_f32_16x16x32_f16(af1, b3,  accB3, 0, 0, 0);
            acclA = __builtin_amdgcn_mfma_f32_16x16x32_f16(af0, vone, acclA, 0, 0, 0);
            acclB = __builtin_amdgcn_mfma_f32_16x16x32_f16(af1, vone, acclB, 0, 0, 0);
        }

        if (hasNext) {
            *reinterpret_cast<half8_t*>(&Bs[cur ^ 1][tid * 8])        = n0;
            *reinterpret_cast<half8_t*>(&Bs[cur ^ 1][2048 + tid * 8]) = n1;
        }
        __syncthreads();
        cur ^= 1;
    }

    float* lp = lbuf + (size_t)jc * (H_HEADS * N_NODES);
    if (mrow == 0) {
        #pragma unroll
        for (int r = 0; r < 4; r++) {
            lp[h * N_NODES + i0 + 4 * gl + r]      = acclA[r];
            lp[h * N_NODES + i0 + 16 + 4 * gl + r] = acclB[r];
        }
    }
    if (jc == 0) {
        #pragma unroll
        for (int r = 0; r < 4; r++) {
            size_t obA = ((size_t)h * N_NODES + i0 + 4 * gl + r) * 64 + mrow;
            size_t obB = ((size_t)h * N_NODES + i0 + 16 + 4 * gl + r) * 64 + mrow;
            out0[obA + 0]  = accA0[r];
            out0[obA + 16] = accA1[r];
            out0[obA + 32] = accA2[r];
            out0[obA + 48] = accA3[r];
            out0[obB + 0]  = accB0[r];
            out0[obB + 16] = accB1[r];
            out0[obB + 32] = accB2[r];
            out0[obB + 48] = accB3[r];
        }
    } else {
        _Float16* op = partH + (size_t)(jc - 1) * ((size_t)H_HEADS * N_NODES * F_OUT);
        #pragma unroll
        for (int r = 0; r < 4; r++) {
            size_t obA = ((size_t)h * N_NODES + i0 + 4 * gl + r) * 64 + mrow;
            size_t obB = ((size_t)h * N_NODES + i0 + 16 + 4 * gl + r) * 64 + mrow;
            op[obA + 0]  = (_Float16)accA0[r];
            op[obA + 16] = (_Float16)accA1[r];
            op[obA + 32] = (_Float16)accA2[r];
            op[obA + 48] = (_Float16)accA3[r];
            op[obB + 0]  = (_Float16)accB0[r];
            op[obB + 16] = (_Float16)accB1[r];
            op[obB + 32] = (_Float16)accB2[r];
            op[obB + 48] = (_Float16)accB3[r];
        }
    }
}

// ---------------- K4: out = (out + sum f16 partials) / sum l ----------------
__global__ __launch_bounds__(256) void k_norm(float* __restrict__ out,
                                              const _Float16* __restrict__ partH,
                                              const float* __restrict__ lbuf) {
    const int HN = H_HEADS * N_NODES;
    int idx = blockIdx.x * 256 + threadIdx.x;        // float4 index
    int row = idx >> 4;
    float inv = 1.0f / (lbuf[row] + lbuf[HN + row] + lbuf[2 * HN + row] + lbuf[3 * HN + row]);
    float4 a = reinterpret_cast<const float4*>(out)[idx];
    float s0 = a.x, s1 = a.y, s2 = a.z, s3 = a.w;
    #pragma unroll
    for (int p = 0; p < 3; p++) {
        half4_t hp = *reinterpret_cast<const half4_t*>(
            &partH[(size_t)p * ((size_t)H_HEADS * N_NODES * F_OUT) + (size_t)idx * 4]);
        s0 += (float)hp[0]; s1 += (float)hp[1]; s2 += (float)hp[2]; s3 += (float)hp[3];
    }
    float4 v = {s0 * inv, s1 * inv, s2 * inv, s3 * inv};
    reinterpret_cast<float4*>(out)[idx] = v;
}

// ---------------- launch ----------------
extern "C" void kernel_launch(void* const* d_in, const int* in_sizes, int n_in,
                              void* d_out, int out_size, void* d_ws, size_t ws_size,
                              hipStream_t stream) {
    const float* x     = (const float*)d_in[0];
    const int*   adj   = (const int*)d_in[1];
    const float* W     = (const float*)d_in[2];
    const float* a_src = (const float*)d_in[3];
    const float* a_tgt = (const float*)d_in[4];
    float* out = (float*)d_out;

    // workspace via accumulating allocator (R7 lesson: no hand-computed offsets)
    char* ws = (char*)d_ws;
    size_t off = 0;
    auto alloc = [&](size_t bytes) -> char* {
        char* p = ws + off;
        off += (bytes + 255) & ~(size_t)255;
        return p;
    };
    _Float16* WhFrag = (_Float16*)alloc((size_t)H_HEADS * N_NODES * F_OUT * 2);        // 4 MB
    _Float16* wfrag  = (_Float16*)alloc((size_t)H_HEADS * 16 * 4 * 64 * 8 * 2);        // 512 KB
    float* s_iL      = (float*)alloc((size_t)H_HEADS * N_NODES * 4);                   // 128 KB
    _Float16* s_jLh  = (_Float16*)alloc((size_t)H_HEADS * N_NODES * 2);                // 64 KB
    float* mxAll     = (float*)alloc((size_t)H_HEADS * 4);                             // 32 B
    float* lbuf      = (float*)alloc((size_t)JC * H_HEADS * N_NODES * 4);              // 512 KB
    _Float16* partH  = (_Float16*)alloc((size_t)(JC - 1) * H_HEADS * N_NODES * F_OUT * 2); // 12 MB
    unsigned long long* adjwT = (unsigned long long*)alloc((size_t)N_NODES * (N_NODES / 64) * 8); // 2 MB
    (void)ws_size;

    k_prep<<<2176, 256, 0, stream>>>(adj, W, adjwT, wfrag);
    k_wh_mfma<<<dim3(N_NODES / 64, H_HEADS), 512, 0, stream>>>(x, wfrag, a_src, a_tgt,
                                                               WhFrag, s_iL, s_jLh);
    k_hmax<<<H_HEADS, 256, 0, stream>>>(s_jLh, mxAll);
    k_attn_mfma<<<dim3(N_NODES / 128, H_HEADS, JC), 256, 0, stream>>>(WhFrag, s_iL, mxAll, s_jLh,
                                                                      adjwT, out, partH, lbuf);
    k_norm<<<(H_HEADS * N_NODES * F_OUT / 4) / 256, 256, 0, stream>>>(out, partH, lbuf);
}